// Round 4
// baseline (447.986 us; speedup 1.0000x reference)
//
#include <hip/hip_runtime.h>
#include <cmath>

// ---------------------------------------------------------------------------
// Poincare transformer layer. Round 13:
//  GEMM inner loop software-pipelined at register level (same sync skeleton):
//   frag reads split kk0/kk1; MFMA(kk0) overlaps kk1 ds_reads; MFMA(kk1)
//   overlaps NEXT tile's kk0 ds_reads (issued after the vmcnt(6)+barrier that
//   guarantees tile t+1 landed). Breaks the lockstep LDS-burst/MFMA-burst
//   alternation seen at 1 block/CU (MfmaUtil 27%, serial LDS+MFMA sum).
//  Attention (R12 counted-vmcnt pipeline) and epilogues unchanged.
// ---------------------------------------------------------------------------

constexpr int kD  = 1024;
constexpr int kH  = 16;
constexpr int kHD = 64;
constexpr int kFF = 4096;
constexpr int kB  = 4;
constexpr int kS  = 1024;
constexpr int kN  = kB * kS;   // 4096 tokens

#define EPSF 1e-7f
#define MTAF (1.0f - 1e-5f)
#define LOG2E 1.4426950408889634f

typedef unsigned int uint32;
typedef unsigned short ushort16;
typedef __attribute__((ext_vector_type(8))) short short8x;
typedef __attribute__((ext_vector_type(4))) float floatx4;

// ---------------- bf16 helpers ----------------
__device__ __forceinline__ ushort16 f2b(float f) {
  union { float f; uint32 u; } x; x.f = f;
  uint32 r = x.u + 0x7fffu + ((x.u >> 16) & 1u);   // RNE
  return (ushort16)(r >> 16);
}
__device__ __forceinline__ float b2f(ushort16 u) {
  union { uint32 u; float f; } x; x.u = ((uint32)u) << 16;
  return x.f;
}
__device__ __forceinline__ void load_b4(const ushort16* p, float v[4]) {
  uint2 u = *(const uint2*)p;
  v[0] = b2f((ushort16)(u.x & 0xffff)); v[1] = b2f((ushort16)(u.x >> 16));
  v[2] = b2f((ushort16)(u.y & 0xffff)); v[3] = b2f((ushort16)(u.y >> 16));
}
__device__ __forceinline__ void store_b4(ushort16* p, const float v[4]) {
  uint2 u;
  u.x = (uint32)f2b(v[0]) | ((uint32)f2b(v[1]) << 16);
  u.y = (uint32)f2b(v[2]) | ((uint32)f2b(v[3]) << 16);
  *(uint2*)p = u;
}

// ---------------- math helpers ----------------
__device__ __forceinline__ float atanh_clipped(float n) {
  float c = fminf(n, MTAF);
  return 0.5f * logf((1.0f + c) / (1.0f - c));
}
__device__ __forceinline__ float logmap0_scale(float nraw) {
  float n = fmaxf(nraw, EPSF);
  return atanh_clipped(n) / n;
}
__device__ __forceinline__ float expmap0_scale(float nraw) {
  float n = fmaxf(nraw, EPSF);
  return tanhf(n) / n;
}
__device__ __forceinline__ float roundtrip_scale(float nraw) {
  float nu = fmaxf(nraw, EPSF);
  float se = tanhf(nu) / nu;
  float nb = fmaxf(se * nraw, EPSF);
  float sl = atanh_clipped(nb) / nb;
  return sl * se;
}

// ---------------- reductions ----------------
__device__ __forceinline__ float blockReduceSum256(float v, float* s4) {
#pragma unroll
  for (int o = 32; o > 0; o >>= 1) v += __shfl_xor(v, o);
  int wave = threadIdx.x >> 6;
  if ((threadIdx.x & 63) == 0) s4[wave] = v;
  __syncthreads();
  float r = s4[0] + s4[1] + s4[2] + s4[3];
  __syncthreads();
  return r;
}
__device__ __forceinline__ float redSum16(float v) {
#pragma unroll
  for (int o = 8; o > 0; o >>= 1) v += __shfl_xor(v, o);
  return v;
}

// ---------------- async global->LDS, 16 bytes/lane ----------------
__device__ __forceinline__ void async16(const void* g, void* l) {
  __builtin_amdgcn_global_load_lds(
      (const __attribute__((address_space(1))) uint32*)g,
      (__attribute__((address_space(3))) uint32*)l, 16, 0, 0);
}

// ---------------- weight transpose + cast: src [K][N] f32 -> dst [N][K] bf16 ----
__device__ __forceinline__ void transpose_tile(const float* __restrict__ src,
                                               ushort16* __restrict__ dst,
                                               int K, int N, int n0, int k0) {
  __shared__ float T[64][65];
  int tid = threadIdx.x;
#pragma unroll
  for (int p = 0; p < 4; ++p) {
    int idx = p * 1024 + tid * 4;
    int r = idx >> 6, c = idx & 63;
    float4 t = *(const float4*)&src[(size_t)(k0 + r) * N + n0 + c];
    T[r][c] = t.x; T[r][c + 1] = t.y; T[r][c + 2] = t.z; T[r][c + 3] = t.w;
  }
  __syncthreads();
#pragma unroll
  for (int p = 0; p < 4; ++p) {
    int idx = p * 1024 + tid * 4;
    int r = idx >> 6, c = idx & 63;
    float v[4] = {T[c][r], T[c + 1][r], T[c + 2][r], T[c + 3][r]};
    store_b4(&dst[(size_t)(n0 + r) * K + k0 + c], v);
  }
}
__global__ __launch_bounds__(256) void k_transpose_bf16(const float* __restrict__ src,
                                                        ushort16* __restrict__ dst,
                                                        int K, int N) {
  transpose_tile(src, dst, K, N, blockIdx.x * 64, blockIdx.y * 64);
}
__global__ __launch_bounds__(256) void k_transpose4(
    const float* __restrict__ s0, const float* __restrict__ s1,
    const float* __restrict__ s2, const float* __restrict__ s3,
    ushort16* __restrict__ d0, ushort16* __restrict__ d1,
    ushort16* __restrict__ d2, ushort16* __restrict__ d3) {
  const float* src = (blockIdx.z == 0) ? s0 : (blockIdx.z == 1) ? s1
                    : (blockIdx.z == 2) ? s2 : s3;
  ushort16* dst = (blockIdx.z == 0) ? d0 : (blockIdx.z == 1) ? d1
                 : (blockIdx.z == 2) ? d2 : d3;
  transpose_tile(src, dst, kD, kD, blockIdx.x * 64, blockIdx.y * 64);
}

// ---------------- ada = t_emb @ w_ada + b_ada (K-chunked GEMV) ----------------
__global__ __launch_bounds__(256) void k_ada(const float* __restrict__ t_emb,
                                             const float* __restrict__ w_ada,
                                             const float* __restrict__ b_ada,
                                             float* __restrict__ ada) {
  __shared__ float te[kD];
  __shared__ float part[4][64];
  int b = blockIdx.y;
  int tid = threadIdx.x;
  {
    float4 t = *(const float4*)&t_emb[b * kD + tid * 4];
    te[tid * 4] = t.x; te[tid * 4 + 1] = t.y; te[tid * 4 + 2] = t.z; te[tid * 4 + 3] = t.w;
  }
  __syncthreads();
  int c = tid & 63, kc = tid >> 6;
  int col = blockIdx.x * 64 + c;
  float acc = 0.f;
#pragma unroll 8
  for (int k = kc * 256; k < kc * 256 + 256; ++k)
    acc += te[k] * w_ada[(size_t)k * (6 * kD) + col];
  part[kc][c] = acc;
  __syncthreads();
  if (tid < 64)
    ada[b * 6 * kD + blockIdx.x * 64 + tid] =
        part[0][tid] + part[1][tid] + part[2][tid] + part[3][tid] +
        b_ada[blockIdx.x * 64 + tid];
}

// ---------------- prenorm -> bf16 GEMM input (vectorized) ----------------
__global__ __launch_bounds__(256) void k_prenorm(const float* __restrict__ x,
                                                 const float* __restrict__ ada,
                                                 int sh_off, int sc_off,
                                                 ushort16* __restrict__ out) {
  __shared__ float sred[4];
  int tok = blockIdx.x;
  int b = tok >> 10;
  int d4 = threadIdx.x * 4;
  float xv[4];
  *(float4*)xv = *(const float4*)&x[(size_t)tok * kD + d4];
  float ss = xv[0] * xv[0] + xv[1] * xv[1] + xv[2] * xv[2] + xv[3] * xv[3];
  ss = blockReduceSum256(ss, sred);
  float sl = logmap0_scale(sqrtf(ss));
  float sum = 0.f;
#pragma unroll
  for (int i = 0; i < 4; ++i) { xv[i] *= sl; sum += xv[i]; }
  sum = blockReduceSum256(sum, sred);
  float mean = sum * (1.0f / kD);
  float vs = 0.f;
#pragma unroll
  for (int i = 0; i < 4; ++i) { xv[i] -= mean; vs += xv[i] * xv[i]; }
  vs = blockReduceSum256(vs, sred);
  float inv = rsqrtf(vs * (1.0f / kD) + 1e-6f);
  float shv[4], scv[4];
  *(float4*)shv = *(const float4*)&ada[b * 6 * kD + sh_off + d4];
  *(float4*)scv = *(const float4*)&ada[b * 6 * kD + sc_off + d4];
  float uu = 0.f;
#pragma unroll
  for (int i = 0; i < 4; ++i) {
    float u = xv[i] * inv * (1.0f + scv[i]) + shv[i];
    xv[i] = u;
    uu += u * u;
  }
  uu = blockReduceSum256(uu, sred);
  float s = roundtrip_scale(sqrtf(uu));
#pragma unroll
  for (int i = 0; i < 4; ++i) xv[i] *= s;
  store_b4(out + (size_t)tok * kD + d4, xv);
}

// ---------------- bf16 MFMA GEMM: C = rowscale ∘ (A @ Bt^T) + bias ----------------
// 256x128 tile, BK=64, 512 threads (8 waves of 64x64), double-buffered LDS,
// 2-tile prefetch with counted vmcnt, register-level kk0/kk1 software pipe:
// MFMA(kk0) overlaps kk1 ds_reads; MFMA(kk1) overlaps next tile's kk0 reads.
// KSPLIT==1: z selects (Bt,bias,C) triple, C dtype per OUT_BF16.
// KSPLIT==2: z = K-half; z=0 -> C0 f32 (+bias), z=1 -> C1 bf16 (no bias).
template <int OUT_BF16, int KSPLIT>
__global__ __launch_bounds__(512, 2) void k_gemm_bf16(
    const ushort16* __restrict__ A,
    const ushort16* __restrict__ Bt0, const ushort16* __restrict__ Bt1,
    const ushort16* __restrict__ Bt2,
    const float* __restrict__ bias0, const float* __restrict__ bias1,
    const float* __restrict__ bias2,
    const float* __restrict__ rowscale,
    void* __restrict__ C0, void* __restrict__ C1, void* __restrict__ C2,
    int M, int N, int K) {
  const ushort16* Bt;
  const float* bias;
  void* C;
  int k_lo, k_hi;
  bool add_bias;
  if (KSPLIT == 1) {
    Bt = (blockIdx.z == 0) ? Bt0 : ((blockIdx.z == 1) ? Bt1 : Bt2);
    bias = (blockIdx.z == 0) ? bias0 : ((blockIdx.z == 1) ? bias1 : bias2);
    C = (blockIdx.z == 0) ? C0 : ((blockIdx.z == 1) ? C1 : C2);
    k_lo = 0; k_hi = K; add_bias = true;
  } else {
    Bt = Bt0; bias = bias0;
    C = (blockIdx.z == 0) ? C0 : C1;
    int kchunk = K / KSPLIT;
    k_lo = blockIdx.z * kchunk; k_hi = k_lo + kchunk;
    add_bias = (blockIdx.z == 0);
  }

  __shared__ __align__(16) ushort16 As[2 * 256 * 64];   // 64 KiB
  __shared__ __align__(16) ushort16 Bs[2 * 128 * 64];   // 32 KiB

  int tid = threadIdx.x;
  int lane = tid & 63;
  int wave = tid >> 6;
  int wr = wave >> 1, wc = wave & 1;       // 4x2 wave grid, 64x64 each
  int c16 = lane & 15, quad = lane >> 4;
  int row0 = blockIdx.x * 256, col0 = blockIdx.y * 128;

  // ---- staging coords (per thread; p-independent swizzle) ----
  int srow = tid >> 3;                               // 0..63
  int scol = (((tid & 7) ^ ((tid >> 4) & 7)) << 3);  // logical col for phys chunk tid&7
  const ushort16* a_src = A + (size_t)(row0 + srow) * K + k_lo + scol;
  const ushort16* b_src = Bt + (size_t)(col0 + srow) * K + k_lo + scol;
  int sdst = tid * 8;
  int nt = (k_hi - k_lo) >> 6;

  auto stage = [&](int tt) {
    int cc = tt & 1;
    size_t ko = (size_t)tt * 64;
#pragma unroll
    for (int p = 0; p < 4; ++p)
      async16(a_src + ko + (size_t)(p * 64) * K, (ushort16*)As + cc * 16384 + p * 4096 + sdst);
#pragma unroll
    for (int p = 0; p < 2; ++p)
      async16(b_src + ko + (size_t)(p * 64) * K, (ushort16*)Bs + cc * 8192 + p * 4096 + sdst);
  };

  // ---- frag read offsets (elements); phys chunk = (kk*4+quad) ^ ((c16>>1)&7) ----
  int xsw = (c16 >> 1) & 7;
  int aoff0 = (wr * 64 + c16) * 64 + ((quad ^ xsw) << 3);
  int aoff1 = (wr * 64 + c16) * 64 + (((4 + quad) ^ xsw) << 3);
  int boff0 = (wc * 64 + c16) * 64 + ((quad ^ xsw) << 3);
  int boff1 = (wc * 64 + c16) * 64 + (((4 + quad) ^ xsw) << 3);

  floatx4 acc[4][4];
#pragma unroll
  for (int i = 0; i < 4; ++i)
#pragma unroll
    for (int j = 0; j < 4; ++j) acc[i][j] = (floatx4)0.f;

  // ---- prologue: tiles 0,1 in flight; wait tile 0 (allow tile 1's 6 loads) ----
  stage(0);
  stage(1);
  asm volatile("s_waitcnt vmcnt(6)" ::: "memory");
  __builtin_amdgcn_s_barrier();

  // kk0 frags of tile 0
  short8x a0[4], b0[4], a1[4], b1[4];
#pragma unroll
  for (int i = 0; i < 4; ++i) {
    a0[i] = *(const short8x*)&((const ushort16*)As)[i * 1024 + aoff0];
    b0[i] = *(const short8x*)&((const ushort16*)Bs)[i * 1024 + boff0];
  }

  for (int t = 0; t < nt; ++t) {
    int cc = t & 1;
    const ushort16* Ab = (const ushort16*)As + cc * 16384;
    const ushort16* Bb = (const ushort16*)Bs + cc * 8192;
    // issue kk1 reads; they fly under the kk0 MFMA cluster
#pragma unroll
    for (int i = 0; i < 4; ++i) {
      a1[i] = *(const short8x*)&Ab[i * 1024 + aoff1];
      b1[i] = *(const short8x*)&Bb[i * 1024 + boff1];
    }
    __builtin_amdgcn_s_setprio(1);
#pragma unroll
    for (int i = 0; i < 4; ++i)
#pragma unroll
      for (int j = 0; j < 4; ++j)
        acc[i][j] = __builtin_amdgcn_mfma_f32_16x16x32_bf16(a0[i], b0[j], acc[i][j], 0, 0, 0);
    __builtin_amdgcn_s_setprio(0);
    // all reads of buf cc done -> fence, then overwrite it with tile t+2
    asm volatile("s_waitcnt lgkmcnt(0)" ::: "memory");
    __builtin_amdgcn_s_barrier();
    if (t + 2 < nt) stage(t + 2);
    // counted wait: tile t+1 landed; tile t+2's 6 loads stay in flight
    if (t + 2 < nt) {
      asm volatile("s_waitcnt vmcnt(6)" ::: "memory");
    } else {
      asm volatile("s_waitcnt vmcnt(0)" ::: "memory");
    }
    __builtin_amdgcn_s_barrier();
    // next tile's kk0 reads; they fly under the kk1 MFMA cluster
    if (t + 1 < nt) {
      const ushort16* Ab2 = (const ushort16*)As + (cc ^ 1) * 16384;
      const ushort16* Bb2 = (const ushort16*)Bs + (cc ^ 1) * 8192;
#pragma unroll
      for (int i = 0; i < 4; ++i) {
        a0[i] = *(const short8x*)&Ab2[i * 1024 + aoff0];
        b0[i] = *(const short8x*)&Bb2[i * 1024 + boff0];
      }
    }
    __builtin_amdgcn_s_setprio(1);
#pragma unroll
    for (int i = 0; i < 4; ++i)
#pragma unroll
      for (int j = 0; j < 4; ++j)
        acc[i][j] = __builtin_amdgcn_mfma_f32_16x16x32_bf16(a1[i], b1[j], acc[i][j], 0, 0, 0);
    __builtin_amdgcn_s_setprio(0);
  }

  float bv[4];
#pragma unroll
  for (int j = 0; j < 4; ++j)
    bv[j] = add_bias ? bias[col0 + wc * 64 + j * 16 + c16] : 0.f;
  int rowq = quad * 4;
#pragma unroll
  for (int i = 0; i < 4; ++i) {
    int rbase = row0 + wr * 64 + i * 16 + rowq;
    float rs4[4];
#pragma unroll
    for (int r = 0; r < 4; ++r) rs4[r] = rowscale ? rowscale[rbase + r] : 1.0f;
#pragma unroll
    for (int j = 0; j < 4; ++j) {
      int c = col0 + wc * 64 + j * 16 + c16;
#pragma unroll
      for (int r = 0; r < 4; ++r) {
        float v = acc[i][j][r] * rs4[r] + bv[j];
        if (KSPLIT == 2) {
          if (blockIdx.z == 0) ((float*)C)[(size_t)(rbase + r) * N + c] = v;
          else ((ushort16*)C)[(size_t)(rbase + r) * N + c] = f2b(v);
        } else if (OUT_BF16) {
          ((ushort16*)C)[(size_t)(rbase + r) * N + c] = f2b(v);
        } else {
          ((float*)C)[(size_t)(rbase + r) * N + c] = v;
        }
      }
    }
  }
}

// ---------------- head split (vectorized) ----------------
__global__ __launch_bounds__(256) void k_headsplit_b(const ushort16* __restrict__ q_in,
                                                     ushort16* __restrict__ k_io,
                                                     ushort16* __restrict__ v_io,
                                                     ushort16* __restrict__ qb_out,
                                                     float ratio) {
  __shared__ float sred[4];
  int tok = blockIdx.x;
  int tid = threadIdx.x;
  int d4 = tid * 4;
#pragma unroll
  for (int t = 0; t < 3; ++t) {
    const ushort16* p = (t == 0 ? q_in : (t == 1 ? (const ushort16*)k_io
                                                 : (const ushort16*)v_io)) +
                        (size_t)tok * kD + d4;
    float val[4];
    load_b4(p, val);
    float psq = val[0] * val[0] + val[1] * val[1] + val[2] * val[2] + val[3] * val[3];
    float hsq = redSum16(psq);
    float tot = blockReduceSum256(psq, sred);
    float s1 = roundtrip_scale(sqrtf(tot));
    float c = s1 * ratio;
    float s2 = roundtrip_scale(c * sqrtf(hsq));
    float f = c * s2 * (t == 0 ? (0.125f * LOG2E) : 1.0f);
#pragma unroll
    for (int i = 0; i < 4; ++i) val[i] *= f;
    ushort16* op = (t == 0 ? qb_out : (t == 1 ? k_io : v_io)) + (size_t)tok * kD + d4;
    store_b4(op, val);
    __syncthreads();
  }
}

// ---------------- V transpose with k-permutation pi(s)=(s&15)*2+(s>>4) ----------------
__global__ __launch_bounds__(256) void k_vtrans_b(const ushort16* __restrict__ v,
                                                  ushort16* __restrict__ vT) {
  __shared__ ushort16 T[64][68];
  int bh = blockIdx.y, b = bh >> 4, h = bh & 15;
  int s0 = blockIdx.x * 64;
  int tid = threadIdx.x;
#pragma unroll
  for (int p = 0; p < 4; ++p) {
    int idx = p * 1024 + tid * 4;
    int r = idx >> 6, d = idx & 63;
    *(uint2*)&T[r][d] = *(const uint2*)&v[(size_t)(b * kS + s0 + r) * kD + h * kHD + d];
  }
  __syncthreads();
#pragma unroll
  for (int p = 0; p < 16; ++p) {
    int idx = p * 256 + tid;
    int d = idx >> 6, c = idx & 63;
    int cp = (c & 32) | ((c & 15) << 1) | ((c >> 4) & 1);
    vT[((size_t)bh * kHD + d) * kS + s0 + cp] = T[c][d];
  }
}

// ---------------- MFMA flash attention, max-free; writes bf16 T IN PLACE ----------------
// QBLK=128, Ks double-buffered, Vs single, counted vmcnt pipeline (R12).
__global__ __launch_bounds__(256) void k_attn_mfma(ushort16* __restrict__ qb,
                                                   const ushort16* __restrict__ kb,
                                                   const ushort16* __restrict__ vT,
                                                   float ratio2) {
  __shared__ __align__(16) ushort16 Ks[2 * 2 * 128 * 32];  // dbuf x [dsub][key][32] swz
  __shared__ __align__(16) ushort16 Vs[4 * 64 * 32];       // [ssub][d][32] swizzled
  __shared__ __align__(16) ushort16 Ps[4 * 4 * 16 * 40];   // [wave][kk][row16][40pad]
  int bh = blockIdx.x, b = bh >> 4, h = bh & 15;
  int q0 = blockIdx.y * 128;
  int tid = threadIdx.x, lane = tid & 63, wave = tid >> 6;
  int c16 = lane & 15, quad = lane >> 4;
  int sw = (lane >> 1) & 3;
  int cbp = ((quad ^ sw) << 3);
  int wq = wave * 32;
  constexpr int NT = kS / 128;   // 8

  short8x a_q[2][2];
#pragma unroll
  for (int i = 0; i < 2; ++i)
#pragma unroll
    for (int kk = 0; kk < 2; ++kk)
      a_q[i][kk] = *(const short8x*)&qb[(size_t)(b * kS + q0 + wq + i * 16 + c16) * kD +
                                        h * kHD + kk * 32 + quad * 8];

  short8x ones;
#pragma unroll
  for (int j = 0; j < 8; ++j) ones[j] = (short)0x3F80;  // bf16 1.0

  floatx4 o[2][4], ol[2];
#pragma unroll
  for (int i = 0; i < 2; ++i) {
    ol[i] = (floatx4)0.f;
#pragma unroll
    for (int n = 0; n < 4; ++n) o[i][n] = (floatx4)0.f;
  }

  const ushort16* kbase = kb + ((size_t)b * kS) * kD + h * kHD;
  const ushort16* vbase = vT + (size_t)bh * kHD * kS;

  auto stageK = [&](int t) {
    int cbuf = t & 1;
#pragma unroll
    for (int tt = 0; tt < 2; ++tt)
#pragma unroll
      for (int cb2 = 0; cb2 < 2; ++cb2) {
        int e = cb2 * 2048 + tid * 8;
        int key = e >> 5;
        int col = ((((e >> 3) & 3) ^ ((key >> 1) & 3)) << 3);
        async16(kbase + (size_t)(t * 128 + key) * kD + tt * 32 + col,
                Ks + cbuf * 8192 + tt * 4096 + e);
      }
  };
  auto stageV = [&](int t) {
#pragma unroll
    for (int tt = 0; tt < 4; ++tt) {
      int e = tid * 8;
      int dd = e >> 5;
      int col = ((((e >> 3) & 3) ^ ((dd >> 1) & 3)) << 3);
      async16(vbase + (size_t)dd * kS + t * 128 + tt * 32 + col, Vs + tt * 2048 + e);
    }
  };

  // prologue: K(0), V(0), K(1) in flight; wait K(0) (8 newer stay in flight)
  stageK(0);
  stageV(0);
  stageK(1);
  asm volatile("s_waitcnt vmcnt(8)" ::: "memory");
  __builtin_amdgcn_s_barrier();

  for (int t = 0; t < NT; ++t) {
    const ushort16* Kc = (const ushort16*)Ks + (t & 1) * 8192;

#pragma unroll
    for (int i = 0; i < 2; ++i) {
      floatx4 s[8];
#pragma unroll
      for (int n = 0; n < 8; ++n) s[n] = (floatx4)0.f;
      __builtin_amdgcn_s_setprio(1);
#pragma unroll
      for (int kkd = 0; kkd < 2; ++kkd)
#pragma unroll
        for (int n = 0; n < 8; ++n) {
          short8x bk = *(const short8x*)&Kc[kkd * 4096 + (n * 16 + c16) * 32 + cbp];
          s[n] = __builtin_amdgcn_mfma_f32_16x16x32_bf16(a_q[i][kkd], bk, s[n], 0, 0, 0);
        }
      __builtin_amdgcn_s_setprio(0);

      // p = exp2(s); hardware packed RNE bf16 convert, permuted k
#pragma unroll
      for (int r = 0; r < 4; ++r) {
#pragma unroll
        for (int j = 0; j < 4; ++j) {
          float e0 = exp2f(s[2 * j][r]);
          float e1 = exp2f(s[2 * j + 1][r]);
          uint32 u;
          asm("v_cvt_pk_bf16_f32 %0, %1, %2" : "=v"(u) : "v"(e0), "v"(e1));
          *(uint32*)&Ps[(((wave * 4 + j) * 16) + (quad * 4 + r)) * 40 + c16 * 2] = u;
        }
      }

      if (i == 0) {
        // V(t) landed (issued one full tile ago); K(t+1)'s 4 loads stay in flight
        if (t + 1 < NT) {
          asm volatile("s_waitcnt vmcnt(4)" ::: "memory");
        } else {
          asm volatile("s_waitcnt vmcnt(0)" ::: "memory");
        }
        __builtin_amdgcn_s_barrier();
      }

      // o += P @ V ; l += P @ ones   (Ps region is per-wave: lgkm handled by compiler)
      __builtin_amdgcn_s_setprio(1);
#pragma unroll
      for (int kk = 0; kk < 4; ++kk) {
        short8x ap = *(const short8x*)&Ps[(((wave * 4 + kk) * 16) + c16) * 40 + quad * 8];
#pragma unroll
        for (int n = 0; n < 4; ++n) {
          short8x bv = *(const short8x*)&Vs[kk * 2048 + (n * 16 + c16) * 32 + cbp];
          o[i][n] = __builtin_amdgcn_mfma_f32_16x16x32_bf16(ap, bv, o[i][n], 0, 0, 0);
        }
        ol[i] = __builtin_amdgcn_mfma_f32_16x16x32_bf16(ap, ones, ol[i], 0, 0, 0);
      }
      __builtin_amdgcn_s_setprio(0);
    }

    // all waves done reading Vs & Ks[t&1]; overwrite them with next tiles
    asm volatile("s_waitcnt lgkmcnt(0)" ::: "memory");
    __builtin_amdgcn_s_barrier();
    if (t + 1 < NT) stageV(t + 1);
    if (t + 2 < NT) stageK(t + 2);
    // wait K(t+1); V(t+1)+K(t+2) (8 loads) stay in flight
    if (t + 2 < NT) {
      asm volatile("s_waitcnt vmcnt(8)" ::: "memory");
    } else if (t + 1 < NT) {
      asm volatile("s_waitcnt vmcnt(4)" ::: "memory");
    } else {
      asm volatile("s_waitcnt vmcnt(0)" ::: "memory");
    }
    __builtin_amdgcn_s_barrier();
  }

  // finalize: w = o/l, per-head rt coef; write bf16 tangent IN PLACE
#pragma unroll
  for (int i = 0; i < 2; ++i)
#pragma unroll
    for (int r = 0; r < 4; ++r) {
      float invl = 1.0f / ol[i][r];
      float w[4];
      float pssq = 0.f;
#pragma unroll
      for (int n = 0; n < 4; ++n) { w[n] = o[i][n][r] * invl; pssq += w[n] * w[n]; }
      float ssq = redSum16(pssq);
      float coef = roundtrip_scale(sqrtf(ssq)) * ratio2;
      int row = b * kS + q0 + wq + i * 16 + quad * 4 + r;
#pragma unroll
      for (int n = 0; n < 4; ++n)
        qb[(size_t)row * kD + h * kHD + n * 16 + c16] = f2b(coef * w[n]);
    }
}

// ---------------- row norm -> roundtrip scale (read-only pass) ----------------
template <int WIDTH>
__global__ __launch_bounds__(256) void k_rowscale(const ushort16* __restrict__ p,
                                                  float* __restrict__ s) {
  __shared__ float sred[4];
  constexpr int PER = WIDTH / 1024;
  size_t base = (size_t)blockIdx.x * WIDTH;
  float ss = 0.f;
#pragma unroll
  for (int i = 0; i < PER; ++i) {
    float v[4];
    load_b4(p + base + i * 1024 + threadIdx.x * 4, v);
    ss += v[0] * v[0] + v[1] * v[1] + v[2] * v[2] + v[3] * v[3];
  }
  ss = blockReduceSum256(ss, sred);
  if (threadIdx.x == 0) s[blockIdx.x] = roundtrip_scale(sqrtf(ss));
}

// ---------------- mobius epilogue core ----------------
__device__ __forceinline__ void mobius_body(float xv[4], float tv[4],
                                            const float* gp, int d4,
                                            float* sred, float outv[4]) {
  float ss = tv[0] * tv[0] + tv[1] * tv[1] + tv[2] * tv[2] + tv[3] * tv[3];
  ss = blockReduceSum256(ss, sred);
  float s5 = roundtrip_scale(sqrtf(ss));
  float gv[4];
  *(float4*)gv = *(const float4*)&gp[d4];
  float at2 = 0.f;
#pragma unroll
  for (int i = 0; i < 4; ++i) {
    float a = gv[i] * s5 * tv[i];
    tv[i] = a;
    at2 += a * a;
  }
  at2 = blockReduceSum256(at2, sred);
  float nyraw = sqrtf(at2);
  float sy = expmap0_scale(nyraw);
  float ynorm = sy * nyraw;
  float y2 = ynorm * ynorm;
  float x2p = 0.f, xyp = 0.f;
#pragma unroll
  for (int i = 0; i < 4; ++i) {
    float y = sy * tv[i];
    tv[i] = y;
    x2p += xv[i] * xv[i];
    xyp += xv[i] * y;
  }
  float x2 = blockReduceSum256(x2p, sred);
  float xy = blockReduceSum256(xyp, sred);
  float cx = 1.0f + 2.0f * xy + y2;
  float cy = 1.0f - x2;
  float den = fmaxf(1.0f + 2.0f * xy + x2 * y2, EPSF);
  float invden = 1.0f / den;
#pragma unroll
  for (int i = 0; i < 4; ++i) outv[i] = (cx * xv[i] + cy * tv[i]) * invden;
}

// final epilogue: out = mobius(xres, expmap0(g*rt(p0 + p1b)))  (p1b bf16)
__global__ __launch_bounds__(256) void k_epilogue2(const float* __restrict__ xres,
                                                   const float* __restrict__ ot0,
                                                   const ushort16* __restrict__ ot1b,
                                                   const float* __restrict__ ada,
                                                   int g_off,
                                                   float* __restrict__ out) {
  __shared__ float sred[4];
  int tok = blockIdx.x;
  int b = tok >> 10;
  size_t base = (size_t)tok * kD;
  int d4 = threadIdx.x * 4;
  float xv[4], tv[4], t1[4];
  *(float4*)tv = *(const float4*)&ot0[base + d4];
  load_b4(ot1b + base + d4, t1);
  *(float4*)xv = *(const float4*)&xres[base + d4];
#pragma unroll
  for (int i = 0; i < 4; ++i) tv[i] += t1[i];
  float outv[4];
  mobius_body(xv, tv, ada + b * 6 * kD + g_off, d4, sred, outv);
  *(float4*)&out[base + d4] = *(float4*)outv;
}

// fused: x_mid = mobius(x, msa partials) -> xmid_out (f32), then prenorm(mlp) -> bf16
__global__ __launch_bounds__(256) void k_epi_pre(const float* __restrict__ xres,
                                                 const float* __restrict__ ot0,
                                                 const ushort16* __restrict__ ot1b,
                                                 const float* __restrict__ ada,
                                                 float* __restrict__ xmid_out,
                                                 ushort16* __restrict__ lx2_out) {
  __shared__ float sred[4];
  int tok = blockIdx.x;
  int b = tok >> 10;
  size_t base = (size_t)tok * kD;
  int d4 = threadIdx.x * 4;
  float xv[4], tv[4], t1[4];
  *(float4*)tv = *(const float4*)&ot0[base + d4];
  load_b4(ot1b + base + d4, t1);
  *(float4*)xv = *(const float4*)&xres[base + d4];
#pragma unroll
  for (int i = 0; i < 4; ++i) tv[i] += t1[i];
  float xm[4];
  mobius_body(xv, tv, ada + b * 6 * kD + 2 * kD, d4, sred, xm);
  *(float4*)&xmid_out[base + d4] = *(float4*)xm;

  float ss = xm[0] * xm[0] + xm[1] * xm[1] + xm[2] * xm[2] + xm[3] * xm[3];
  ss = blockReduceSum256(ss, sred);
  float sl = logmap0_scale(sqrtf(ss));
  float sum = 0.f;
#pragma unroll
  for (int i = 0; i < 4; ++i) { xm[i] *= sl; sum += xm[i]; }
  sum = blockReduceSum256(sum, sred);
  float mean = sum * (1.0f / kD);
  float vs = 0.f;
#pragma unroll
  for (int i = 0; i < 4; ++i) { xm[i] -= mean; vs += xm[i] * xm[i]; }
  vs = blockReduceSum256(vs, sred);
  float inv = rsqrtf(vs * (1.0f / kD) + 1e-6f);
  float shv[4], scv[4];
  *(float4*)shv = *(const float4*)&ada[b * 6 * kD + 3 * kD + d4];
  *(float4*)scv = *(const float4*)&ada[b * 6 * kD + 4 * kD + d4];
  float uu = 0.f;
#pragma unroll
  for (int i = 0; i < 4; ++i) {
    float u = xm[i] * inv * (1.0f + scv[i]) + shv[i];
    xm[i] = u;
    uu += u * u;
  }
  uu = blockReduceSum256(uu, sred);
  float s = roundtrip_scale(sqrtf(uu));
#pragma unroll
  for (int i = 0; i < 4; ++i) xm[i] *= s;
  store_b4(lx2_out + base + d4, xm);
}

// ---------------------------------------------------------------------------
extern "C" void kernel_launch(void* const* d_in, const int* in_sizes, int n_in,
                              void* d_out, int out_size, void* d_ws, size_t ws_size,
                              hipStream_t stream) {
  const float* x     = (const float*)d_in[0];
  const float* t_emb = (const float*)d_in[1];
  const float* w_q = (const float*)d_in[2];  const float* b_q = (const float*)d_in[3];
  const float* w_k = (const float*)d_in[4];  const float* b_k = (const float*)d_in[5];
  const float* w_v = (const float*)d_in[6];  const float* b_v = (const float*)d_in[7];
  const float* w_o = (const float*)d_in[8];  const float* b_o = (const float*)d_in[9];
  const float* w_f1 = (const float*)d_in[10]; const float* b_f1 = (const float*)d_in[11];
  const float* w_f2 = (const float*)d_in[12]; const float* b_f2 = (const float*)d_in[13];
  const float* w_ada = (const float*)d_in[14]; const float* b_ada = (const float*)d_in[15];
  float* out = (float*)d_out;

  constexpr size_t ND = (size_t)kN * kD;    // 4 M
  constexpr size_t NF = (size_t)kN * kFF;   // 16 M
  constexpr size_t DD = (size_t)kD * kD;    // 1 M

  float* ws   = (float*)d_ws;
  float* ada  = ws;                 // 24576 f32
  float* qt   = ada + 6 * kD * kB;  // ND f32 (split-K partial 0, f32+bias)
  float* kt   = qt + ND;            // ND f32 (rowscale arrays: 4096 floats)
  float* vt   = kt + ND;            // ND f32 (x_mid)
  ushort16* qbA = (ushort16*)(vt + ND);   // ND bf16 (lx / qb / attn-T / lx2)
  ushort16* kb  = qbA + ND;               // ND bf16 (q raw -> vT -> bf16 partial1)
  ushort16* vTb = kb + ND;                // ND bf16 (k raw -> k scaled)
  ushort16* actB = vTb + ND;              // NF bf16 (v raw/scaled; h1)
  ushort16* wqT  = actB + NF;             // DD bf16 each
  ushort16* wkT  = wqT + DD;
  ushort16* wvT  = wkT + DD;
  ushort16* woT  = wvT + DD;
  ushort16* wf1T = woT + DD;              // FF*D
  ushort16* wf2T = wf1T + (size_t)kD * kFF;

  double bn = exp(lgamma(512.0) + lgamma(0.5) - lgamma(512.5));
  double bh = exp(lgamma(32.0) + lgamma(0.5) - lgamma(32.5));
  float R1 = (float)(bh / bn);
  float R2 = (float)(bn / bh);

  // 0) weight transposes + cast to bf16 [N][K]
  k_transpose4<<<dim3(16, 16, 4), 256, 0, stream>>>(w_q, w_k, w_v, w_o,
                                                    wqT, wkT, wvT, woT);
  k_transpose_bf16<<<dim3(64, 16), 256, 0, stream>>>(w_f1, wf1T, kD, kFF);
  k_transpose_bf16<<<dim3(16, 64), 256, 0, stream>>>(w_f2, wf2T, kFF, kD);
  // 1) ada
  k_ada<<<dim3(6 * kD / 64, kB), 256, 0, stream>>>(t_emb, w_ada, b_ada, ada);
  // 2) prenorm (msa): lx -> qbA (bf16)
  k_prenorm<<<kN, 256, 0, stream>>>(x, ada, 0 * kD, 1 * kD, qbA);
  // 3) q,k,v projections, bf16 out: q->kb, k->vTb, v->actB
  k_gemm_bf16<1, 1><<<dim3(kN / 256, kD / 128, 3), 512, 0, stream>>>(
      qbA, wqT, wkT, wvT, b_q, b_k, b_v, nullptr, kb, vTb, actB, kN, kD, kD);
  // 4) head split: qb->qbA (pre-scaled 0.125*log2e), k in vTb, v in actB
  k_headsplit_b<<<kN, 256, 0, stream>>>(kb, vTb, actB, qbA, R1);
  // 5) V transpose (k-permuted): actB -> kb
  k_vtrans_b<<<dim3(kS / 64, kB * kH), 256, 0, stream>>>(actB, kb);
  // 6) attention (max-free): reads qbA, writes bf16 tangent T in place
  k_attn_mfma<<<dim3(kB * kH, kS / 128), 256, 0, stream>>>(qbA, vTb, kb, R2);
  // 7) row scales for the concat-roundtrip: s[tok] from |T| -> kt
  k_rowscale<kD><<<kN, 256, 0, stream>>>(qbA, kt);
  // 8) o projection, split-K=2, row-scaled: partials qt (f32,+bias), kb (bf16)
  k_gemm_bf16<0, 2><<<dim3(kN / 256, kD / 128, 2), 512, 0, stream>>>(
      qbA, woT, woT, woT, b_o, b_o, b_o, kt, qt, kb, nullptr, kN, kD, kD);
  // 9+10) fused mobius epilogue (msa) + prenorm (mlp): vt <- x_mid, qbA <- lx2
  k_epi_pre<<<kN, 256, 0, stream>>>(x, qt, kb, ada, vt, qbA);
  // 11) f1 -> actB (raw h1, bf16)
  k_gemm_bf16<1, 1><<<dim3(kN / 256, kFF / 128, 1), 512, 0, stream>>>(
      qbA, wf1T, wf1T, wf1T, b_f1, b_f1, b_f1, nullptr, actB, actB, actB, kN, kFF, kD);
  // 12) row scales for rt(h1) -> kt
  k_rowscale<kFF><<<kN, 256, 0, stream>>>(actB, kt);
  // 13) f2, split-K=2, row-scaled: partials qt (f32,+bias), kb (bf16)
  k_gemm_bf16<0, 2><<<dim3(kN / 256, kD / 128, 2), 512, 0, stream>>>(
      actB, wf2T, wf2T, wf2T, b_f2, b_f2, b_f2, kt, qt, kb, nullptr, kN, kD, kFF);
  // 14) mobius epilogue (mlp): out = mobius(vt, qt + kb)
  k_epilogue2<<<kN, 256, 0, stream>>>(vt, qt, kb, ada, 5 * kD, out);

  (void)in_sizes; (void)n_in; (void)out_size; (void)ws_size;
}

// Round 5
// 432.169 us; speedup vs baseline: 1.0366x; 1.0366x over previous
//
#include <hip/hip_runtime.h>
#include <cmath>

// ---------------------------------------------------------------------------
// Poincare transformer layer. Round 14:
//  R13's kk0/kk1 rotation reverted (it put lgkm(0)+bar+stage+vmcnt+bar back-
//  to-back with no compute between the waits -> regression). GEMM back to the
//  R10 skeleton but with BK=32: LDS 96->48 KB => 2 blocks/CU (16 waves/CU,
//  VGPR-capped) so the per-step barrier/staging drains of one block hide
//  behind the other block's MFMA+LDS work (m114 inter-wave overlap).
//  Counted vmcnt kept (stage=3 loads, steady-state vmcnt(3), never 0).
//  Attention (R12 counted-vmcnt pipeline) and epilogues unchanged.
// ---------------------------------------------------------------------------

constexpr int kD  = 1024;
constexpr int kH  = 16;
constexpr int kHD = 64;
constexpr int kFF = 4096;
constexpr int kB  = 4;
constexpr int kS  = 1024;
constexpr int kN  = kB * kS;   // 4096 tokens

#define EPSF 1e-7f
#define MTAF (1.0f - 1e-5f)
#define LOG2E 1.4426950408889634f

typedef unsigned int uint32;
typedef unsigned short ushort16;
typedef __attribute__((ext_vector_type(8))) short short8x;
typedef __attribute__((ext_vector_type(4))) float floatx4;

// ---------------- bf16 helpers ----------------
__device__ __forceinline__ ushort16 f2b(float f) {
  union { float f; uint32 u; } x; x.f = f;
  uint32 r = x.u + 0x7fffu + ((x.u >> 16) & 1u);   // RNE
  return (ushort16)(r >> 16);
}
__device__ __forceinline__ float b2f(ushort16 u) {
  union { uint32 u; float f; } x; x.u = ((uint32)u) << 16;
  return x.f;
}
__device__ __forceinline__ void load_b4(const ushort16* p, float v[4]) {
  uint2 u = *(const uint2*)p;
  v[0] = b2f((ushort16)(u.x & 0xffff)); v[1] = b2f((ushort16)(u.x >> 16));
  v[2] = b2f((ushort16)(u.y & 0xffff)); v[3] = b2f((ushort16)(u.y >> 16));
}
__device__ __forceinline__ void store_b4(ushort16* p, const float v[4]) {
  uint2 u;
  u.x = (uint32)f2b(v[0]) | ((uint32)f2b(v[1]) << 16);
  u.y = (uint32)f2b(v[2]) | ((uint32)f2b(v[3]) << 16);
  *(uint2*)p = u;
}

// ---------------- math helpers ----------------
__device__ __forceinline__ float atanh_clipped(float n) {
  float c = fminf(n, MTAF);
  return 0.5f * logf((1.0f + c) / (1.0f - c));
}
__device__ __forceinline__ float logmap0_scale(float nraw) {
  float n = fmaxf(nraw, EPSF);
  return atanh_clipped(n) / n;
}
__device__ __forceinline__ float expmap0_scale(float nraw) {
  float n = fmaxf(nraw, EPSF);
  return tanhf(n) / n;
}
__device__ __forceinline__ float roundtrip_scale(float nraw) {
  float nu = fmaxf(nraw, EPSF);
  float se = tanhf(nu) / nu;
  float nb = fmaxf(se * nraw, EPSF);
  float sl = atanh_clipped(nb) / nb;
  return sl * se;
}

// ---------------- reductions ----------------
__device__ __forceinline__ float blockReduceSum256(float v, float* s4) {
#pragma unroll
  for (int o = 32; o > 0; o >>= 1) v += __shfl_xor(v, o);
  int wave = threadIdx.x >> 6;
  if ((threadIdx.x & 63) == 0) s4[wave] = v;
  __syncthreads();
  float r = s4[0] + s4[1] + s4[2] + s4[3];
  __syncthreads();
  return r;
}
__device__ __forceinline__ float redSum16(float v) {
#pragma unroll
  for (int o = 8; o > 0; o >>= 1) v += __shfl_xor(v, o);
  return v;
}

// ---------------- async global->LDS, 16 bytes/lane ----------------
__device__ __forceinline__ void async16(const void* g, void* l) {
  __builtin_amdgcn_global_load_lds(
      (const __attribute__((address_space(1))) uint32*)g,
      (__attribute__((address_space(3))) uint32*)l, 16, 0, 0);
}

// ---------------- weight transpose + cast: src [K][N] f32 -> dst [N][K] bf16 ----
__device__ __forceinline__ void transpose_tile(const float* __restrict__ src,
                                               ushort16* __restrict__ dst,
                                               int K, int N, int n0, int k0) {
  __shared__ float T[64][65];
  int tid = threadIdx.x;
#pragma unroll
  for (int p = 0; p < 4; ++p) {
    int idx = p * 1024 + tid * 4;
    int r = idx >> 6, c = idx & 63;
    float4 t = *(const float4*)&src[(size_t)(k0 + r) * N + n0 + c];
    T[r][c] = t.x; T[r][c + 1] = t.y; T[r][c + 2] = t.z; T[r][c + 3] = t.w;
  }
  __syncthreads();
#pragma unroll
  for (int p = 0; p < 4; ++p) {
    int idx = p * 1024 + tid * 4;
    int r = idx >> 6, c = idx & 63;
    float v[4] = {T[c][r], T[c + 1][r], T[c + 2][r], T[c + 3][r]};
    store_b4(&dst[(size_t)(n0 + r) * K + k0 + c], v);
  }
}
__global__ __launch_bounds__(256) void k_transpose_bf16(const float* __restrict__ src,
                                                        ushort16* __restrict__ dst,
                                                        int K, int N) {
  transpose_tile(src, dst, K, N, blockIdx.x * 64, blockIdx.y * 64);
}
__global__ __launch_bounds__(256) void k_transpose4(
    const float* __restrict__ s0, const float* __restrict__ s1,
    const float* __restrict__ s2, const float* __restrict__ s3,
    ushort16* __restrict__ d0, ushort16* __restrict__ d1,
    ushort16* __restrict__ d2, ushort16* __restrict__ d3) {
  const float* src = (blockIdx.z == 0) ? s0 : (blockIdx.z == 1) ? s1
                    : (blockIdx.z == 2) ? s2 : s3;
  ushort16* dst = (blockIdx.z == 0) ? d0 : (blockIdx.z == 1) ? d1
                 : (blockIdx.z == 2) ? d2 : d3;
  transpose_tile(src, dst, kD, kD, blockIdx.x * 64, blockIdx.y * 64);
}

// ---------------- ada = t_emb @ w_ada + b_ada (K-chunked GEMV) ----------------
__global__ __launch_bounds__(256) void k_ada(const float* __restrict__ t_emb,
                                             const float* __restrict__ w_ada,
                                             const float* __restrict__ b_ada,
                                             float* __restrict__ ada) {
  __shared__ float te[kD];
  __shared__ float part[4][64];
  int b = blockIdx.y;
  int tid = threadIdx.x;
  {
    float4 t = *(const float4*)&t_emb[b * kD + tid * 4];
    te[tid * 4] = t.x; te[tid * 4 + 1] = t.y; te[tid * 4 + 2] = t.z; te[tid * 4 + 3] = t.w;
  }
  __syncthreads();
  int c = tid & 63, kc = tid >> 6;
  int col = blockIdx.x * 64 + c;
  float acc = 0.f;
#pragma unroll 8
  for (int k = kc * 256; k < kc * 256 + 256; ++k)
    acc += te[k] * w_ada[(size_t)k * (6 * kD) + col];
  part[kc][c] = acc;
  __syncthreads();
  if (tid < 64)
    ada[b * 6 * kD + blockIdx.x * 64 + tid] =
        part[0][tid] + part[1][tid] + part[2][tid] + part[3][tid] +
        b_ada[blockIdx.x * 64 + tid];
}

// ---------------- prenorm -> bf16 GEMM input (vectorized) ----------------
__global__ __launch_bounds__(256) void k_prenorm(const float* __restrict__ x,
                                                 const float* __restrict__ ada,
                                                 int sh_off, int sc_off,
                                                 ushort16* __restrict__ out) {
  __shared__ float sred[4];
  int tok = blockIdx.x;
  int b = tok >> 10;
  int d4 = threadIdx.x * 4;
  float xv[4];
  *(float4*)xv = *(const float4*)&x[(size_t)tok * kD + d4];
  float ss = xv[0] * xv[0] + xv[1] * xv[1] + xv[2] * xv[2] + xv[3] * xv[3];
  ss = blockReduceSum256(ss, sred);
  float sl = logmap0_scale(sqrtf(ss));
  float sum = 0.f;
#pragma unroll
  for (int i = 0; i < 4; ++i) { xv[i] *= sl; sum += xv[i]; }
  sum = blockReduceSum256(sum, sred);
  float mean = sum * (1.0f / kD);
  float vs = 0.f;
#pragma unroll
  for (int i = 0; i < 4; ++i) { xv[i] -= mean; vs += xv[i] * xv[i]; }
  vs = blockReduceSum256(vs, sred);
  float inv = rsqrtf(vs * (1.0f / kD) + 1e-6f);
  float shv[4], scv[4];
  *(float4*)shv = *(const float4*)&ada[b * 6 * kD + sh_off + d4];
  *(float4*)scv = *(const float4*)&ada[b * 6 * kD + sc_off + d4];
  float uu = 0.f;
#pragma unroll
  for (int i = 0; i < 4; ++i) {
    float u = xv[i] * inv * (1.0f + scv[i]) + shv[i];
    xv[i] = u;
    uu += u * u;
  }
  uu = blockReduceSum256(uu, sred);
  float s = roundtrip_scale(sqrtf(uu));
#pragma unroll
  for (int i = 0; i < 4; ++i) xv[i] *= s;
  store_b4(out + (size_t)tok * kD + d4, xv);
}

// ---------------- bf16 MFMA GEMM: C = rowscale ∘ (A @ Bt^T) + bias ----------------
// 256x128 tile, BK=32, 512 threads (8 waves of 64x64), double-buffered LDS
// (48 KB -> 2 blocks/CU), 2-tile prefetch with counted vmcnt (stage=3 loads,
// steady-state vmcnt(3)). XOR-swizzled staging (4 chunks, proven R9 pattern).
// KSPLIT==1: z selects (Bt,bias,C) triple, C dtype per OUT_BF16.
// KSPLIT==2: z = K-half; z=0 -> C0 f32 (+bias), z=1 -> C1 bf16 (no bias).
template <int OUT_BF16, int KSPLIT>
__global__ __launch_bounds__(512, 4) void k_gemm_bf16(
    const ushort16* __restrict__ A,
    const ushort16* __restrict__ Bt0, const ushort16* __restrict__ Bt1,
    const ushort16* __restrict__ Bt2,
    const float* __restrict__ bias0, const float* __restrict__ bias1,
    const float* __restrict__ bias2,
    const float* __restrict__ rowscale,
    void* __restrict__ C0, void* __restrict__ C1, void* __restrict__ C2,
    int M, int N, int K) {
  const ushort16* Bt;
  const float* bias;
  void* C;
  int k_lo, k_hi;
  bool add_bias;
  if (KSPLIT == 1) {
    Bt = (blockIdx.z == 0) ? Bt0 : ((blockIdx.z == 1) ? Bt1 : Bt2);
    bias = (blockIdx.z == 0) ? bias0 : ((blockIdx.z == 1) ? bias1 : bias2);
    C = (blockIdx.z == 0) ? C0 : ((blockIdx.z == 1) ? C1 : C2);
    k_lo = 0; k_hi = K; add_bias = true;
  } else {
    Bt = Bt0; bias = bias0;
    C = (blockIdx.z == 0) ? C0 : C1;
    int kchunk = K / KSPLIT;
    k_lo = blockIdx.z * kchunk; k_hi = k_lo + kchunk;
    add_bias = (blockIdx.z == 0);
  }

  __shared__ __align__(16) ushort16 As[2 * 256 * 32];   // 32 KiB
  __shared__ __align__(16) ushort16 Bs[2 * 128 * 32];   // 16 KiB

  int tid = threadIdx.x;
  int lane = tid & 63;
  int wave = tid >> 6;
  int wr = wave >> 1, wc = wave & 1;       // 4x2 wave grid, 64x64 each
  int c16 = lane & 15, quad = lane >> 4;
  int row0 = blockIdx.x * 256, col0 = blockIdx.y * 128;

  // ---- staging coords: 512 threads, 8 elem each; row = tid>>2 (0..127),
  //      phys chunk tid&3 holds logical chunk (tid&3)^((row>>1)&3) ----
  int srow = tid >> 2;
  int scol = (((tid & 3) ^ ((tid >> 3) & 3)) << 3);
  const ushort16* a_src = A + (size_t)(row0 + srow) * K + k_lo + scol;
  const ushort16* b_src = Bt + (size_t)(col0 + srow) * K + k_lo + scol;
  int sdst = tid * 8;
  int nt = (k_hi - k_lo) >> 5;

  auto stage = [&](int tt) {
    int cc = tt & 1;
    size_t ko = (size_t)tt * 32;
    async16(a_src + ko, (ushort16*)As + cc * 8192 + sdst);
    async16(a_src + ko + (size_t)128 * K, (ushort16*)As + cc * 8192 + 4096 + sdst);
    async16(b_src + ko, (ushort16*)Bs + cc * 4096 + sdst);
  };

  // ---- frag read offsets; phys chunk = quad ^ ((c16>>1)&3) ----
  int sw3 = (c16 >> 1) & 3;
  int cbp = ((quad ^ sw3) << 3);
  int aoff = (wr * 64 + c16) * 32 + cbp;
  int boff = (wc * 64 + c16) * 32 + cbp;

  floatx4 acc[4][4];
#pragma unroll
  for (int i = 0; i < 4; ++i)
#pragma unroll
    for (int j = 0; j < 4; ++j) acc[i][j] = (floatx4)0.f;

  // ---- prologue: tiles 0,1 in flight; wait tile 0 (tile 1's 3 loads fly) ----
  stage(0);
  stage(1);
  asm volatile("s_waitcnt vmcnt(3)" ::: "memory");
  __builtin_amdgcn_s_barrier();

  for (int t = 0; t < nt; ++t) {
    int cc = t & 1;
    const ushort16* Ab = (const ushort16*)As + cc * 8192;
    const ushort16* Bb = (const ushort16*)Bs + cc * 4096;
    short8x a[4], b[4];
#pragma unroll
    for (int i = 0; i < 4; ++i) {
      a[i] = *(const short8x*)&Ab[i * 512 + aoff];
      b[i] = *(const short8x*)&Bb[i * 512 + boff];
    }
    __builtin_amdgcn_s_setprio(1);
#pragma unroll
    for (int i = 0; i < 4; ++i)
#pragma unroll
      for (int j = 0; j < 4; ++j)
        acc[i][j] = __builtin_amdgcn_mfma_f32_16x16x32_bf16(a[i], b[j], acc[i][j], 0, 0, 0);
    __builtin_amdgcn_s_setprio(0);
    // reads of buf cc done -> fence, then overwrite it with tile t+2
    asm volatile("s_waitcnt lgkmcnt(0)" ::: "memory");
    __builtin_amdgcn_s_barrier();
    if (t + 2 < nt) {
      stage(t + 2);
      // counted wait: tile t+1 landed; tile t+2's 3 loads stay in flight
      asm volatile("s_waitcnt vmcnt(3)" ::: "memory");
    } else {
      asm volatile("s_waitcnt vmcnt(0)" ::: "memory");
    }
    __builtin_amdgcn_s_barrier();
  }

  float bv[4];
#pragma unroll
  for (int j = 0; j < 4; ++j)
    bv[j] = add_bias ? bias[col0 + wc * 64 + j * 16 + c16] : 0.f;
  int rowq = quad * 4;
#pragma unroll
  for (int i = 0; i < 4; ++i) {
    int rbase = row0 + wr * 64 + i * 16 + rowq;
    float rs4[4];
#pragma unroll
    for (int r = 0; r < 4; ++r) rs4[r] = rowscale ? rowscale[rbase + r] : 1.0f;
#pragma unroll
    for (int j = 0; j < 4; ++j) {
      int c = col0 + wc * 64 + j * 16 + c16;
#pragma unroll
      for (int r = 0; r < 4; ++r) {
        float v = acc[i][j][r] * rs4[r] + bv[j];
        if (KSPLIT == 2) {
          if (blockIdx.z == 0) ((float*)C)[(size_t)(rbase + r) * N + c] = v;
          else ((ushort16*)C)[(size_t)(rbase + r) * N + c] = f2b(v);
        } else if (OUT_BF16) {
          ((ushort16*)C)[(size_t)(rbase + r) * N + c] = f2b(v);
        } else {
          ((float*)C)[(size_t)(rbase + r) * N + c] = v;
        }
      }
    }
  }
}

// ---------------- head split (vectorized) ----------------
__global__ __launch_bounds__(256) void k_headsplit_b(const ushort16* __restrict__ q_in,
                                                     ushort16* __restrict__ k_io,
                                                     ushort16* __restrict__ v_io,
                                                     ushort16* __restrict__ qb_out,
                                                     float ratio) {
  __shared__ float sred[4];
  int tok = blockIdx.x;
  int tid = threadIdx.x;
  int d4 = tid * 4;
#pragma unroll
  for (int t = 0; t < 3; ++t) {
    const ushort16* p = (t == 0 ? q_in : (t == 1 ? (const ushort16*)k_io
                                                 : (const ushort16*)v_io)) +
                        (size_t)tok * kD + d4;
    float val[4];
    load_b4(p, val);
    float psq = val[0] * val[0] + val[1] * val[1] + val[2] * val[2] + val[3] * val[3];
    float hsq = redSum16(psq);
    float tot = blockReduceSum256(psq, sred);
    float s1 = roundtrip_scale(sqrtf(tot));
    float c = s1 * ratio;
    float s2 = roundtrip_scale(c * sqrtf(hsq));
    float f = c * s2 * (t == 0 ? (0.125f * LOG2E) : 1.0f);
#pragma unroll
    for (int i = 0; i < 4; ++i) val[i] *= f;
    ushort16* op = (t == 0 ? qb_out : (t == 1 ? k_io : v_io)) + (size_t)tok * kD + d4;
    store_b4(op, val);
    __syncthreads();
  }
}

// ---------------- V transpose with k-permutation pi(s)=(s&15)*2+(s>>4) ----------------
__global__ __launch_bounds__(256) void k_vtrans_b(const ushort16* __restrict__ v,
                                                  ushort16* __restrict__ vT) {
  __shared__ ushort16 T[64][68];
  int bh = blockIdx.y, b = bh >> 4, h = bh & 15;
  int s0 = blockIdx.x * 64;
  int tid = threadIdx.x;
#pragma unroll
  for (int p = 0; p < 4; ++p) {
    int idx = p * 1024 + tid * 4;
    int r = idx >> 6, d = idx & 63;
    *(uint2*)&T[r][d] = *(const uint2*)&v[(size_t)(b * kS + s0 + r) * kD + h * kHD + d];
  }
  __syncthreads();
#pragma unroll
  for (int p = 0; p < 16; ++p) {
    int idx = p * 256 + tid;
    int d = idx >> 6, c = idx & 63;
    int cp = (c & 32) | ((c & 15) << 1) | ((c >> 4) & 1);
    vT[((size_t)bh * kHD + d) * kS + s0 + cp] = T[c][d];
  }
}

// ---------------- MFMA flash attention, max-free; writes bf16 T IN PLACE ----------------
// QBLK=128, Ks double-buffered, Vs single, counted vmcnt pipeline (R12).
__global__ __launch_bounds__(256) void k_attn_mfma(ushort16* __restrict__ qb,
                                                   const ushort16* __restrict__ kb,
                                                   const ushort16* __restrict__ vT,
                                                   float ratio2) {
  __shared__ __align__(16) ushort16 Ks[2 * 2 * 128 * 32];  // dbuf x [dsub][key][32] swz
  __shared__ __align__(16) ushort16 Vs[4 * 64 * 32];       // [ssub][d][32] swizzled
  __shared__ __align__(16) ushort16 Ps[4 * 4 * 16 * 40];   // [wave][kk][row16][40pad]
  int bh = blockIdx.x, b = bh >> 4, h = bh & 15;
  int q0 = blockIdx.y * 128;
  int tid = threadIdx.x, lane = tid & 63, wave = tid >> 6;
  int c16 = lane & 15, quad = lane >> 4;
  int sw = (lane >> 1) & 3;
  int cbp = ((quad ^ sw) << 3);
  int wq = wave * 32;
  constexpr int NT = kS / 128;   // 8

  short8x a_q[2][2];
#pragma unroll
  for (int i = 0; i < 2; ++i)
#pragma unroll
    for (int kk = 0; kk < 2; ++kk)
      a_q[i][kk] = *(const short8x*)&qb[(size_t)(b * kS + q0 + wq + i * 16 + c16) * kD +
                                        h * kHD + kk * 32 + quad * 8];

  short8x ones;
#pragma unroll
  for (int j = 0; j < 8; ++j) ones[j] = (short)0x3F80;  // bf16 1.0

  floatx4 o[2][4], ol[2];
#pragma unroll
  for (int i = 0; i < 2; ++i) {
    ol[i] = (floatx4)0.f;
#pragma unroll
    for (int n = 0; n < 4; ++n) o[i][n] = (floatx4)0.f;
  }

  const ushort16* kbase = kb + ((size_t)b * kS) * kD + h * kHD;
  const ushort16* vbase = vT + (size_t)bh * kHD * kS;

  auto stageK = [&](int t) {
    int cbuf = t & 1;
#pragma unroll
    for (int tt = 0; tt < 2; ++tt)
#pragma unroll
      for (int cb2 = 0; cb2 < 2; ++cb2) {
        int e = cb2 * 2048 + tid * 8;
        int key = e >> 5;
        int col = ((((e >> 3) & 3) ^ ((key >> 1) & 3)) << 3);
        async16(kbase + (size_t)(t * 128 + key) * kD + tt * 32 + col,
                Ks + cbuf * 8192 + tt * 4096 + e);
      }
  };
  auto stageV = [&](int t) {
#pragma unroll
    for (int tt = 0; tt < 4; ++tt) {
      int e = tid * 8;
      int dd = e >> 5;
      int col = ((((e >> 3) & 3) ^ ((dd >> 1) & 3)) << 3);
      async16(vbase + (size_t)dd * kS + t * 128 + tt * 32 + col, Vs + tt * 2048 + e);
    }
  };

  // prologue: K(0), V(0), K(1) in flight; wait K(0) (8 newer stay in flight)
  stageK(0);
  stageV(0);
  stageK(1);
  asm volatile("s_waitcnt vmcnt(8)" ::: "memory");
  __builtin_amdgcn_s_barrier();

  for (int t = 0; t < NT; ++t) {
    const ushort16* Kc = (const ushort16*)Ks + (t & 1) * 8192;

#pragma unroll
    for (int i = 0; i < 2; ++i) {
      floatx4 s[8];
#pragma unroll
      for (int n = 0; n < 8; ++n) s[n] = (floatx4)0.f;
      __builtin_amdgcn_s_setprio(1);
#pragma unroll
      for (int kkd = 0; kkd < 2; ++kkd)
#pragma unroll
        for (int n = 0; n < 8; ++n) {
          short8x bk = *(const short8x*)&Kc[kkd * 4096 + (n * 16 + c16) * 32 + cbp];
          s[n] = __builtin_amdgcn_mfma_f32_16x16x32_bf16(a_q[i][kkd], bk, s[n], 0, 0, 0);
        }
      __builtin_amdgcn_s_setprio(0);

      // p = exp2(s); hardware packed RNE bf16 convert, permuted k
#pragma unroll
      for (int r = 0; r < 4; ++r) {
#pragma unroll
        for (int j = 0; j < 4; ++j) {
          float e0 = exp2f(s[2 * j][r]);
          float e1 = exp2f(s[2 * j + 1][r]);
          uint32 u;
          asm("v_cvt_pk_bf16_f32 %0, %1, %2" : "=v"(u) : "v"(e0), "v"(e1));
          *(uint32*)&Ps[(((wave * 4 + j) * 16) + (quad * 4 + r)) * 40 + c16 * 2] = u;
        }
      }

      if (i == 0) {
        // V(t) landed (issued one full tile ago); K(t+1)'s 4 loads stay in flight
        if (t + 1 < NT) {
          asm volatile("s_waitcnt vmcnt(4)" ::: "memory");
        } else {
          asm volatile("s_waitcnt vmcnt(0)" ::: "memory");
        }
        __builtin_amdgcn_s_barrier();
      }

      // o += P @ V ; l += P @ ones   (Ps region is per-wave: lgkm handled by compiler)
      __builtin_amdgcn_s_setprio(1);
#pragma unroll
      for (int kk = 0; kk < 4; ++kk) {
        short8x ap = *(const short8x*)&Ps[(((wave * 4 + kk) * 16) + c16) * 40 + quad * 8];
#pragma unroll
        for (int n = 0; n < 4; ++n) {
          short8x bv = *(const short8x*)&Vs[kk * 2048 + (n * 16 + c16) * 32 + cbp];
          o[i][n] = __builtin_amdgcn_mfma_f32_16x16x32_bf16(ap, bv, o[i][n], 0, 0, 0);
        }
        ol[i] = __builtin_amdgcn_mfma_f32_16x16x32_bf16(ap, ones, ol[i], 0, 0, 0);
      }
      __builtin_amdgcn_s_setprio(0);
    }

    // all waves done reading Vs & Ks[t&1]; overwrite them with next tiles
    asm volatile("s_waitcnt lgkmcnt(0)" ::: "memory");
    __builtin_amdgcn_s_barrier();
    if (t + 1 < NT) stageV(t + 1);
    if (t + 2 < NT) stageK(t + 2);
    // wait K(t+1); V(t+1)+K(t+2) (8 loads) stay in flight
    if (t + 2 < NT) {
      asm volatile("s_waitcnt vmcnt(8)" ::: "memory");
    } else if (t + 1 < NT) {
      asm volatile("s_waitcnt vmcnt(4)" ::: "memory");
    } else {
      asm volatile("s_waitcnt vmcnt(0)" ::: "memory");
    }
    __builtin_amdgcn_s_barrier();
  }

  // finalize: w = o/l, per-head rt coef; write bf16 tangent IN PLACE
#pragma unroll
  for (int i = 0; i < 2; ++i)
#pragma unroll
    for (int r = 0; r < 4; ++r) {
      float invl = 1.0f / ol[i][r];
      float w[4];
      float pssq = 0.f;
#pragma unroll
      for (int n = 0; n < 4; ++n) { w[n] = o[i][n][r] * invl; pssq += w[n] * w[n]; }
      float ssq = redSum16(pssq);
      float coef = roundtrip_scale(sqrtf(ssq)) * ratio2;
      int row = b * kS + q0 + wq + i * 16 + quad * 4 + r;
#pragma unroll
      for (int n = 0; n < 4; ++n)
        qb[(size_t)row * kD + h * kHD + n * 16 + c16] = f2b(coef * w[n]);
    }
}

// ---------------- row norm -> roundtrip scale (read-only pass) ----------------
template <int WIDTH>
__global__ __launch_bounds__(256) void k_rowscale(const ushort16* __restrict__ p,
                                                  float* __restrict__ s) {
  __shared__ float sred[4];
  constexpr int PER = WIDTH / 1024;
  size_t base = (size_t)blockIdx.x * WIDTH;
  float ss = 0.f;
#pragma unroll
  for (int i = 0; i < PER; ++i) {
    float v[4];
    load_b4(p + base + i * 1024 + threadIdx.x * 4, v);
    ss += v[0] * v[0] + v[1] * v[1] + v[2] * v[2] + v[3] * v[3];
  }
  ss = blockReduceSum256(ss, sred);
  if (threadIdx.x == 0) s[blockIdx.x] = roundtrip_scale(sqrtf(ss));
}

// ---------------- mobius epilogue core ----------------
__device__ __forceinline__ void mobius_body(float xv[4], float tv[4],
                                            const float* gp, int d4,
                                            float* sred, float outv[4]) {
  float ss = tv[0] * tv[0] + tv[1] * tv[1] + tv[2] * tv[2] + tv[3] * tv[3];
  ss = blockReduceSum256(ss, sred);
  float s5 = roundtrip_scale(sqrtf(ss));
  float gv[4];
  *(float4*)gv = *(const float4*)&gp[d4];
  float at2 = 0.f;
#pragma unroll
  for (int i = 0; i < 4; ++i) {
    float a = gv[i] * s5 * tv[i];
    tv[i] = a;
    at2 += a * a;
  }
  at2 = blockReduceSum256(at2, sred);
  float nyraw = sqrtf(at2);
  float sy = expmap0_scale(nyraw);
  float ynorm = sy * nyraw;
  float y2 = ynorm * ynorm;
  float x2p = 0.f, xyp = 0.f;
#pragma unroll
  for (int i = 0; i < 4; ++i) {
    float y = sy * tv[i];
    tv[i] = y;
    x2p += xv[i] * xv[i];
    xyp += xv[i] * y;
  }
  float x2 = blockReduceSum256(x2p, sred);
  float xy = blockReduceSum256(xyp, sred);
  float cx = 1.0f + 2.0f * xy + y2;
  float cy = 1.0f - x2;
  float den = fmaxf(1.0f + 2.0f * xy + x2 * y2, EPSF);
  float invden = 1.0f / den;
#pragma unroll
  for (int i = 0; i < 4; ++i) outv[i] = (cx * xv[i] + cy * tv[i]) * invden;
}

// final epilogue: out = mobius(xres, expmap0(g*rt(p0 + p1b)))  (p1b bf16)
__global__ __launch_bounds__(256) void k_epilogue2(const float* __restrict__ xres,
                                                   const float* __restrict__ ot0,
                                                   const ushort16* __restrict__ ot1b,
                                                   const float* __restrict__ ada,
                                                   int g_off,
                                                   float* __restrict__ out) {
  __shared__ float sred[4];
  int tok = blockIdx.x;
  int b = tok >> 10;
  size_t base = (size_t)tok * kD;
  int d4 = threadIdx.x * 4;
  float xv[4], tv[4], t1[4];
  *(float4*)tv = *(const float4*)&ot0[base + d4];
  load_b4(ot1b + base + d4, t1);
  *(float4*)xv = *(const float4*)&xres[base + d4];
#pragma unroll
  for (int i = 0; i < 4; ++i) tv[i] += t1[i];
  float outv[4];
  mobius_body(xv, tv, ada + b * 6 * kD + g_off, d4, sred, outv);
  *(float4*)&out[base + d4] = *(float4*)outv;
}

// fused: x_mid = mobius(x, msa partials) -> xmid_out (f32), then prenorm(mlp) -> bf16
__global__ __launch_bounds__(256) void k_epi_pre(const float* __restrict__ xres,
                                                 const float* __restrict__ ot0,
                                                 const ushort16* __restrict__ ot1b,
                                                 const float* __restrict__ ada,
                                                 float* __restrict__ xmid_out,
                                                 ushort16* __restrict__ lx2_out) {
  __shared__ float sred[4];
  int tok = blockIdx.x;
  int b = tok >> 10;
  size_t base = (size_t)tok * kD;
  int d4 = threadIdx.x * 4;
  float xv[4], tv[4], t1[4];
  *(float4*)tv = *(const float4*)&ot0[base + d4];
  load_b4(ot1b + base + d4, t1);
  *(float4*)xv = *(const float4*)&xres[base + d4];
#pragma unroll
  for (int i = 0; i < 4; ++i) tv[i] += t1[i];
  float xm[4];
  mobius_body(xv, tv, ada + b * 6 * kD + 2 * kD, d4, sred, xm);
  *(float4*)&xmid_out[base + d4] = *(float4*)xm;

  float ss = xm[0] * xm[0] + xm[1] * xm[1] + xm[2] * xm[2] + xm[3] * xm[3];
  ss = blockReduceSum256(ss, sred);
  float sl = logmap0_scale(sqrtf(ss));
  float sum = 0.f;
#pragma unroll
  for (int i = 0; i < 4; ++i) { xm[i] *= sl; sum += xm[i]; }
  sum = blockReduceSum256(sum, sred);
  float mean = sum * (1.0f / kD);
  float vs = 0.f;
#pragma unroll
  for (int i = 0; i < 4; ++i) { xm[i] -= mean; vs += xm[i] * xm[i]; }
  vs = blockReduceSum256(vs, sred);
  float inv = rsqrtf(vs * (1.0f / kD) + 1e-6f);
  float shv[4], scv[4];
  *(float4*)shv = *(const float4*)&ada[b * 6 * kD + 3 * kD + d4];
  *(float4*)scv = *(const float4*)&ada[b * 6 * kD + 4 * kD + d4];
  float uu = 0.f;
#pragma unroll
  for (int i = 0; i < 4; ++i) {
    float u = xm[i] * inv * (1.0f + scv[i]) + shv[i];
    xm[i] = u;
    uu += u * u;
  }
  uu = blockReduceSum256(uu, sred);
  float s = roundtrip_scale(sqrtf(uu));
#pragma unroll
  for (int i = 0; i < 4; ++i) xm[i] *= s;
  store_b4(lx2_out + base + d4, xm);
}

// ---------------------------------------------------------------------------
extern "C" void kernel_launch(void* const* d_in, const int* in_sizes, int n_in,
                              void* d_out, int out_size, void* d_ws, size_t ws_size,
                              hipStream_t stream) {
  const float* x     = (const float*)d_in[0];
  const float* t_emb = (const float*)d_in[1];
  const float* w_q = (const float*)d_in[2];  const float* b_q = (const float*)d_in[3];
  const float* w_k = (const float*)d_in[4];  const float* b_k = (const float*)d_in[5];
  const float* w_v = (const float*)d_in[6];  const float* b_v = (const float*)d_in[7];
  const float* w_o = (const float*)d_in[8];  const float* b_o = (const float*)d_in[9];
  const float* w_f1 = (const float*)d_in[10]; const float* b_f1 = (const float*)d_in[11];
  const float* w_f2 = (const float*)d_in[12]; const float* b_f2 = (const float*)d_in[13];
  const float* w_ada = (const float*)d_in[14]; const float* b_ada = (const float*)d_in[15];
  float* out = (float*)d_out;

  constexpr size_t ND = (size_t)kN * kD;    // 4 M
  constexpr size_t NF = (size_t)kN * kFF;   // 16 M
  constexpr size_t DD = (size_t)kD * kD;    // 1 M

  float* ws   = (float*)d_ws;
  float* ada  = ws;                 // 24576 f32
  float* qt   = ada + 6 * kD * kB;  // ND f32 (split-K partial 0, f32+bias)
  float* kt   = qt + ND;            // ND f32 (rowscale arrays: 4096 floats)
  float* vt   = kt + ND;            // ND f32 (x_mid)
  ushort16* qbA = (ushort16*)(vt + ND);   // ND bf16 (lx / qb / attn-T / lx2)
  ushort16* kb  = qbA + ND;               // ND bf16 (q raw -> vT -> bf16 partial1)
  ushort16* vTb = kb + ND;                // ND bf16 (k raw -> k scaled)
  ushort16* actB = vTb + ND;              // NF bf16 (v raw/scaled; h1)
  ushort16* wqT  = actB + NF;             // DD bf16 each
  ushort16* wkT  = wqT + DD;
  ushort16* wvT  = wkT + DD;
  ushort16* woT  = wvT + DD;
  ushort16* wf1T = woT + DD;              // FF*D
  ushort16* wf2T = wf1T + (size_t)kD * kFF;

  double bn = exp(lgamma(512.0) + lgamma(0.5) - lgamma(512.5));
  double bh = exp(lgamma(32.0) + lgamma(0.5) - lgamma(32.5));
  float R1 = (float)(bh / bn);
  float R2 = (float)(bn / bh);

  // 0) weight transposes + cast to bf16 [N][K]
  k_transpose4<<<dim3(16, 16, 4), 256, 0, stream>>>(w_q, w_k, w_v, w_o,
                                                    wqT, wkT, wvT, woT);
  k_transpose_bf16<<<dim3(64, 16), 256, 0, stream>>>(w_f1, wf1T, kD, kFF);
  k_transpose_bf16<<<dim3(16, 64), 256, 0, stream>>>(w_f2, wf2T, kFF, kD);
  // 1) ada
  k_ada<<<dim3(6 * kD / 64, kB), 256, 0, stream>>>(t_emb, w_ada, b_ada, ada);
  // 2) prenorm (msa): lx -> qbA (bf16)
  k_prenorm<<<kN, 256, 0, stream>>>(x, ada, 0 * kD, 1 * kD, qbA);
  // 3) q,k,v projections, bf16 out: q->kb, k->vTb, v->actB
  k_gemm_bf16<1, 1><<<dim3(kN / 256, kD / 128, 3), 512, 0, stream>>>(
      qbA, wqT, wkT, wvT, b_q, b_k, b_v, nullptr, kb, vTb, actB, kN, kD, kD);
  // 4) head split: qb->qbA (pre-scaled 0.125*log2e), k in vTb, v in actB
  k_headsplit_b<<<kN, 256, 0, stream>>>(kb, vTb, actB, qbA, R1);
  // 5) V transpose (k-permuted): actB -> kb
  k_vtrans_b<<<dim3(kS / 64, kB * kH), 256, 0, stream>>>(actB, kb);
  // 6) attention (max-free): reads qbA, writes bf16 tangent T in place
  k_attn_mfma<<<dim3(kB * kH, kS / 128), 256, 0, stream>>>(qbA, vTb, kb, R2);
  // 7) row scales for the concat-roundtrip: s[tok] from |T| -> kt
  k_rowscale<kD><<<kN, 256, 0, stream>>>(qbA, kt);
  // 8) o projection, split-K=2, row-scaled: partials qt (f32,+bias), kb (bf16)
  k_gemm_bf16<0, 2><<<dim3(kN / 256, kD / 128, 2), 512, 0, stream>>>(
      qbA, woT, woT, woT, b_o, b_o, b_o, kt, qt, kb, nullptr, kN, kD, kD);
  // 9+10) fused mobius epilogue (msa) + prenorm (mlp): vt <- x_mid, qbA <- lx2
  k_epi_pre<<<kN, 256, 0, stream>>>(x, qt, kb, ada, vt, qbA);
  // 11) f1 -> actB (raw h1, bf16)
  k_gemm_bf16<1, 1><<<dim3(kN / 256, kFF / 128, 1), 512, 0, stream>>>(
      qbA, wf1T, wf1T, wf1T, b_f1, b_f1, b_f1, nullptr, actB, actB, actB, kN, kFF, kD);
  // 12) row scales for rt(h1) -> kt
  k_rowscale<kFF><<<kN, 256, 0, stream>>>(actB, kt);
  // 13) f2, split-K=2, row-scaled: partials qt (f32,+bias), kb (bf16)
  k_gemm_bf16<0, 2><<<dim3(kN / 256, kD / 128, 2), 512, 0, stream>>>(
      actB, wf2T, wf2T, wf2T, b_f2, b_f2, b_f2, kt, qt, kb, nullptr, kN, kD, kFF);
  // 14) mobius epilogue (mlp): out = mobius(vt, qt + kb)
  k_epilogue2<<<kN, 256, 0, stream>>>(vt, qt, kb, ada, 5 * kD, out);

  (void)in_sizes; (void)n_in; (void)out_size; (void)ws_size;
}

// Round 6
// 409.258 us; speedup vs baseline: 1.0946x; 1.0560x over previous
//
#include <hip/hip_runtime.h>
#include <cmath>

// ---------------------------------------------------------------------------
// Poincare transformer layer. Round 15:
//  GEMM: 128x128 tile, BK=64 (R10's proven K-step), 256 threads (4 waves,
//  2x2 of 64x64), double-buffered LDS = 64 KB -> 2 RESIDENT blocks/CU on
//  EVERY gemm (grids: qkv 768, o 512, f1 1024, f2 512 — all >= 2/CU).
//  R14 showed residency is grid-limited for o/f2 (256 blocks); this fixes it
//  without changing barrier-steps per K. Counted vmcnt(8), never 0 in steady
//  state; same R9 XOR swizzle (algebra unchanged at BM=128).
//  Attention (R12 counted-vmcnt pipeline) and epilogues unchanged.
// ---------------------------------------------------------------------------

constexpr int kD  = 1024;
constexpr int kH  = 16;
constexpr int kHD = 64;
constexpr int kFF = 4096;
constexpr int kB  = 4;
constexpr int kS  = 1024;
constexpr int kN  = kB * kS;   // 4096 tokens

#define EPSF 1e-7f
#define MTAF (1.0f - 1e-5f)
#define LOG2E 1.4426950408889634f

typedef unsigned int uint32;
typedef unsigned short ushort16;
typedef __attribute__((ext_vector_type(8))) short short8x;
typedef __attribute__((ext_vector_type(4))) float floatx4;

// ---------------- bf16 helpers ----------------
__device__ __forceinline__ ushort16 f2b(float f) {
  union { float f; uint32 u; } x; x.f = f;
  uint32 r = x.u + 0x7fffu + ((x.u >> 16) & 1u);   // RNE
  return (ushort16)(r >> 16);
}
__device__ __forceinline__ float b2f(ushort16 u) {
  union { uint32 u; float f; } x; x.u = ((uint32)u) << 16;
  return x.f;
}
__device__ __forceinline__ void load_b4(const ushort16* p, float v[4]) {
  uint2 u = *(const uint2*)p;
  v[0] = b2f((ushort16)(u.x & 0xffff)); v[1] = b2f((ushort16)(u.x >> 16));
  v[2] = b2f((ushort16)(u.y & 0xffff)); v[3] = b2f((ushort16)(u.y >> 16));
}
__device__ __forceinline__ void store_b4(ushort16* p, const float v[4]) {
  uint2 u;
  u.x = (uint32)f2b(v[0]) | ((uint32)f2b(v[1]) << 16);
  u.y = (uint32)f2b(v[2]) | ((uint32)f2b(v[3]) << 16);
  *(uint2*)p = u;
}

// ---------------- math helpers ----------------
__device__ __forceinline__ float atanh_clipped(float n) {
  float c = fminf(n, MTAF);
  return 0.5f * logf((1.0f + c) / (1.0f - c));
}
__device__ __forceinline__ float logmap0_scale(float nraw) {
  float n = fmaxf(nraw, EPSF);
  return atanh_clipped(n) / n;
}
__device__ __forceinline__ float expmap0_scale(float nraw) {
  float n = fmaxf(nraw, EPSF);
  return tanhf(n) / n;
}
__device__ __forceinline__ float roundtrip_scale(float nraw) {
  float nu = fmaxf(nraw, EPSF);
  float se = tanhf(nu) / nu;
  float nb = fmaxf(se * nraw, EPSF);
  float sl = atanh_clipped(nb) / nb;
  return sl * se;
}

// ---------------- reductions ----------------
__device__ __forceinline__ float blockReduceSum256(float v, float* s4) {
#pragma unroll
  for (int o = 32; o > 0; o >>= 1) v += __shfl_xor(v, o);
  int wave = threadIdx.x >> 6;
  if ((threadIdx.x & 63) == 0) s4[wave] = v;
  __syncthreads();
  float r = s4[0] + s4[1] + s4[2] + s4[3];
  __syncthreads();
  return r;
}
__device__ __forceinline__ float redSum16(float v) {
#pragma unroll
  for (int o = 8; o > 0; o >>= 1) v += __shfl_xor(v, o);
  return v;
}

// ---------------- async global->LDS, 16 bytes/lane ----------------
__device__ __forceinline__ void async16(const void* g, void* l) {
  __builtin_amdgcn_global_load_lds(
      (const __attribute__((address_space(1))) uint32*)g,
      (__attribute__((address_space(3))) uint32*)l, 16, 0, 0);
}

// ---------------- weight transpose + cast: src [K][N] f32 -> dst [N][K] bf16 ----
__device__ __forceinline__ void transpose_tile(const float* __restrict__ src,
                                               ushort16* __restrict__ dst,
                                               int K, int N, int n0, int k0) {
  __shared__ float T[64][65];
  int tid = threadIdx.x;
#pragma unroll
  for (int p = 0; p < 4; ++p) {
    int idx = p * 1024 + tid * 4;
    int r = idx >> 6, c = idx & 63;
    float4 t = *(const float4*)&src[(size_t)(k0 + r) * N + n0 + c];
    T[r][c] = t.x; T[r][c + 1] = t.y; T[r][c + 2] = t.z; T[r][c + 3] = t.w;
  }
  __syncthreads();
#pragma unroll
  for (int p = 0; p < 4; ++p) {
    int idx = p * 1024 + tid * 4;
    int r = idx >> 6, c = idx & 63;
    float v[4] = {T[c][r], T[c + 1][r], T[c + 2][r], T[c + 3][r]};
    store_b4(&dst[(size_t)(n0 + r) * K + k0 + c], v);
  }
}
__global__ __launch_bounds__(256) void k_transpose_bf16(const float* __restrict__ src,
                                                        ushort16* __restrict__ dst,
                                                        int K, int N) {
  transpose_tile(src, dst, K, N, blockIdx.x * 64, blockIdx.y * 64);
}
__global__ __launch_bounds__(256) void k_transpose4(
    const float* __restrict__ s0, const float* __restrict__ s1,
    const float* __restrict__ s2, const float* __restrict__ s3,
    ushort16* __restrict__ d0, ushort16* __restrict__ d1,
    ushort16* __restrict__ d2, ushort16* __restrict__ d3) {
  const float* src = (blockIdx.z == 0) ? s0 : (blockIdx.z == 1) ? s1
                    : (blockIdx.z == 2) ? s2 : s3;
  ushort16* dst = (blockIdx.z == 0) ? d0 : (blockIdx.z == 1) ? d1
                 : (blockIdx.z == 2) ? d2 : d3;
  transpose_tile(src, dst, kD, kD, blockIdx.x * 64, blockIdx.y * 64);
}

// ---------------- ada = t_emb @ w_ada + b_ada (K-chunked GEMV) ----------------
__global__ __launch_bounds__(256) void k_ada(const float* __restrict__ t_emb,
                                             const float* __restrict__ w_ada,
                                             const float* __restrict__ b_ada,
                                             float* __restrict__ ada) {
  __shared__ float te[kD];
  __shared__ float part[4][64];
  int b = blockIdx.y;
  int tid = threadIdx.x;
  {
    float4 t = *(const float4*)&t_emb[b * kD + tid * 4];
    te[tid * 4] = t.x; te[tid * 4 + 1] = t.y; te[tid * 4 + 2] = t.z; te[tid * 4 + 3] = t.w;
  }
  __syncthreads();
  int c = tid & 63, kc = tid >> 6;
  int col = blockIdx.x * 64 + c;
  float acc = 0.f;
#pragma unroll 8
  for (int k = kc * 256; k < kc * 256 + 256; ++k)
    acc += te[k] * w_ada[(size_t)k * (6 * kD) + col];
  part[kc][c] = acc;
  __syncthreads();
  if (tid < 64)
    ada[b * 6 * kD + blockIdx.x * 64 + tid] =
        part[0][tid] + part[1][tid] + part[2][tid] + part[3][tid] +
        b_ada[blockIdx.x * 64 + tid];
}

// ---------------- prenorm -> bf16 GEMM input (vectorized) ----------------
__global__ __launch_bounds__(256) void k_prenorm(const float* __restrict__ x,
                                                 const float* __restrict__ ada,
                                                 int sh_off, int sc_off,
                                                 ushort16* __restrict__ out) {
  __shared__ float sred[4];
  int tok = blockIdx.x;
  int b = tok >> 10;
  int d4 = threadIdx.x * 4;
  float xv[4];
  *(float4*)xv = *(const float4*)&x[(size_t)tok * kD + d4];
  float ss = xv[0] * xv[0] + xv[1] * xv[1] + xv[2] * xv[2] + xv[3] * xv[3];
  ss = blockReduceSum256(ss, sred);
  float sl = logmap0_scale(sqrtf(ss));
  float sum = 0.f;
#pragma unroll
  for (int i = 0; i < 4; ++i) { xv[i] *= sl; sum += xv[i]; }
  sum = blockReduceSum256(sum, sred);
  float mean = sum * (1.0f / kD);
  float vs = 0.f;
#pragma unroll
  for (int i = 0; i < 4; ++i) { xv[i] -= mean; vs += xv[i] * xv[i]; }
  vs = blockReduceSum256(vs, sred);
  float inv = rsqrtf(vs * (1.0f / kD) + 1e-6f);
  float shv[4], scv[4];
  *(float4*)shv = *(const float4*)&ada[b * 6 * kD + sh_off + d4];
  *(float4*)scv = *(const float4*)&ada[b * 6 * kD + sc_off + d4];
  float uu = 0.f;
#pragma unroll
  for (int i = 0; i < 4; ++i) {
    float u = xv[i] * inv * (1.0f + scv[i]) + shv[i];
    xv[i] = u;
    uu += u * u;
  }
  uu = blockReduceSum256(uu, sred);
  float s = roundtrip_scale(sqrtf(uu));
#pragma unroll
  for (int i = 0; i < 4; ++i) xv[i] *= s;
  store_b4(out + (size_t)tok * kD + d4, xv);
}

// ---------------- bf16 MFMA GEMM: C = rowscale ∘ (A @ Bt^T) + bias ----------------
// 128x128 tile, BK=64, 256 threads (4 waves, 2x2 of 64x64), double-buffered
// LDS (64 KB -> 2 resident blocks/CU), 2-tile prefetch with counted vmcnt
// (stage = 8 loads, steady-state vmcnt(8), never 0). XOR-swizzled staging.
// KSPLIT==1: z selects (Bt,bias,C) triple, C dtype per OUT_BF16.
// KSPLIT==2: z = K-half; z=0 -> C0 f32 (+bias), z=1 -> C1 bf16 (no bias).
template <int OUT_BF16, int KSPLIT>
__global__ __launch_bounds__(256, 2) void k_gemm_bf16(
    const ushort16* __restrict__ A,
    const ushort16* __restrict__ Bt0, const ushort16* __restrict__ Bt1,
    const ushort16* __restrict__ Bt2,
    const float* __restrict__ bias0, const float* __restrict__ bias1,
    const float* __restrict__ bias2,
    const float* __restrict__ rowscale,
    void* __restrict__ C0, void* __restrict__ C1, void* __restrict__ C2,
    int M, int N, int K) {
  const ushort16* Bt;
  const float* bias;
  void* C;
  int k_lo, k_hi;
  bool add_bias;
  if (KSPLIT == 1) {
    Bt = (blockIdx.z == 0) ? Bt0 : ((blockIdx.z == 1) ? Bt1 : Bt2);
    bias = (blockIdx.z == 0) ? bias0 : ((blockIdx.z == 1) ? bias1 : bias2);
    C = (blockIdx.z == 0) ? C0 : ((blockIdx.z == 1) ? C1 : C2);
    k_lo = 0; k_hi = K; add_bias = true;
  } else {
    Bt = Bt0; bias = bias0;
    C = (blockIdx.z == 0) ? C0 : C1;
    int kchunk = K / KSPLIT;
    k_lo = blockIdx.z * kchunk; k_hi = k_lo + kchunk;
    add_bias = (blockIdx.z == 0);
  }

  __shared__ __align__(16) ushort16 As[2 * 128 * 64];   // 32 KiB
  __shared__ __align__(16) ushort16 Bs[2 * 128 * 64];   // 32 KiB

  int tid = threadIdx.x;
  int lane = tid & 63;
  int wave = tid >> 6;
  int wr = (wave >> 1) & 1, wc = wave & 1;   // 2x2 wave grid, 64x64 each
  int c16 = lane & 15, quad = lane >> 4;
  int row0 = blockIdx.x * 128, col0 = blockIdx.y * 128;

  // ---- staging coords: 256 threads, 8 elem each; srow = tid>>3 (0..31),
  //      phys chunk tid&7 holds logical chunk (tid&7)^((srow>>1)&7) ----
  int srow = tid >> 3;
  int scol = (((tid & 7) ^ ((tid >> 4) & 7)) << 3);
  const ushort16* a_src = A + (size_t)(row0 + srow) * K + k_lo + scol;
  const ushort16* b_src = Bt + (size_t)(col0 + srow) * K + k_lo + scol;
  int sdst = tid * 8;
  int nt = (k_hi - k_lo) >> 6;

  auto stage = [&](int tt) {
    int cc = tt & 1;
    size_t ko = (size_t)tt * 64;
#pragma unroll
    for (int p = 0; p < 4; ++p) {
      async16(a_src + ko + (size_t)(p * 32) * K, (ushort16*)As + cc * 8192 + p * 2048 + sdst);
      async16(b_src + ko + (size_t)(p * 32) * K, (ushort16*)Bs + cc * 8192 + p * 2048 + sdst);
    }
  };

  // ---- frag read offsets (elements); phys chunk = (kk*4+quad) ^ ((c16>>1)&7) ----
  int xsw = (c16 >> 1) & 7;
  int aoff0 = (wr * 64 + c16) * 64 + ((quad ^ xsw) << 3);
  int aoff1 = (wr * 64 + c16) * 64 + (((4 + quad) ^ xsw) << 3);
  int boff0 = (wc * 64 + c16) * 64 + ((quad ^ xsw) << 3);
  int boff1 = (wc * 64 + c16) * 64 + (((4 + quad) ^ xsw) << 3);

  floatx4 acc[4][4];
#pragma unroll
  for (int i = 0; i < 4; ++i)
#pragma unroll
    for (int j = 0; j < 4; ++j) acc[i][j] = (floatx4)0.f;

  // ---- prologue: tiles 0,1 in flight; wait tile 0 (tile 1's 8 loads fly) ----
  stage(0);
  stage(1);
  asm volatile("s_waitcnt vmcnt(8)" ::: "memory");
  __builtin_amdgcn_s_barrier();

  for (int t = 0; t < nt; ++t) {
    int cc = t & 1;
    const ushort16* Ab = (const ushort16*)As + cc * 8192;
    const ushort16* Bb = (const ushort16*)Bs + cc * 8192;
    short8x a[4][2], b[4][2];
#pragma unroll
    for (int i = 0; i < 4; ++i) {
      a[i][0] = *(const short8x*)&Ab[i * 1024 + aoff0];
      a[i][1] = *(const short8x*)&Ab[i * 1024 + aoff1];
      b[i][0] = *(const short8x*)&Bb[i * 1024 + boff0];
      b[i][1] = *(const short8x*)&Bb[i * 1024 + boff1];
    }
    // kk=0 MFMAs overlap the kk=1 reads still in flight (compiler lgkmcnt)
    __builtin_amdgcn_s_setprio(1);
#pragma unroll
    for (int i = 0; i < 4; ++i)
#pragma unroll
      for (int j = 0; j < 4; ++j)
        acc[i][j] = __builtin_amdgcn_mfma_f32_16x16x32_bf16(a[i][0], b[j][0], acc[i][j], 0, 0, 0);
    __builtin_amdgcn_s_setprio(0);
    // block-wide read fence of buf cc, then overwrite it with tile t+2
    asm volatile("s_waitcnt lgkmcnt(0)" ::: "memory");
    __builtin_amdgcn_s_barrier();
    if (t + 2 < nt) stage(t + 2);
    __builtin_amdgcn_s_setprio(1);
#pragma unroll
    for (int i = 0; i < 4; ++i)
#pragma unroll
      for (int j = 0; j < 4; ++j)
        acc[i][j] = __builtin_amdgcn_mfma_f32_16x16x32_bf16(a[i][1], b[j][1], acc[i][j], 0, 0, 0);
    __builtin_amdgcn_s_setprio(0);
    // counted wait: tile t+1 landed; tile t+2's 8 loads stay in flight
    if (t + 2 < nt) {
      asm volatile("s_waitcnt vmcnt(8)" ::: "memory");
    } else {
      asm volatile("s_waitcnt vmcnt(0)" ::: "memory");
    }
    __builtin_amdgcn_s_barrier();
  }

  float bv[4];
#pragma unroll
  for (int j = 0; j < 4; ++j)
    bv[j] = add_bias ? bias[col0 + wc * 64 + j * 16 + c16] : 0.f;
  int rowq = quad * 4;
#pragma unroll
  for (int i = 0; i < 4; ++i) {
    int rbase = row0 + wr * 64 + i * 16 + rowq;
    float rs4[4];
#pragma unroll
    for (int r = 0; r < 4; ++r) rs4[r] = rowscale ? rowscale[rbase + r] : 1.0f;
#pragma unroll
    for (int j = 0; j < 4; ++j) {
      int c = col0 + wc * 64 + j * 16 + c16;
#pragma unroll
      for (int r = 0; r < 4; ++r) {
        float v = acc[i][j][r] * rs4[r] + bv[j];
        if (KSPLIT == 2) {
          if (blockIdx.z == 0) ((float*)C)[(size_t)(rbase + r) * N + c] = v;
          else ((ushort16*)C)[(size_t)(rbase + r) * N + c] = f2b(v);
        } else if (OUT_BF16) {
          ((ushort16*)C)[(size_t)(rbase + r) * N + c] = f2b(v);
        } else {
          ((float*)C)[(size_t)(rbase + r) * N + c] = v;
        }
      }
    }
  }
}

// ---------------- head split (vectorized) ----------------
__global__ __launch_bounds__(256) void k_headsplit_b(const ushort16* __restrict__ q_in,
                                                     ushort16* __restrict__ k_io,
                                                     ushort16* __restrict__ v_io,
                                                     ushort16* __restrict__ qb_out,
                                                     float ratio) {
  __shared__ float sred[4];
  int tok = blockIdx.x;
  int tid = threadIdx.x;
  int d4 = tid * 4;
#pragma unroll
  for (int t = 0; t < 3; ++t) {
    const ushort16* p = (t == 0 ? q_in : (t == 1 ? (const ushort16*)k_io
                                                 : (const ushort16*)v_io)) +
                        (size_t)tok * kD + d4;
    float val[4];
    load_b4(p, val);
    float psq = val[0] * val[0] + val[1] * val[1] + val[2] * val[2] + val[3] * val[3];
    float hsq = redSum16(psq);
    float tot = blockReduceSum256(psq, sred);
    float s1 = roundtrip_scale(sqrtf(tot));
    float c = s1 * ratio;
    float s2 = roundtrip_scale(c * sqrtf(hsq));
    float f = c * s2 * (t == 0 ? (0.125f * LOG2E) : 1.0f);
#pragma unroll
    for (int i = 0; i < 4; ++i) val[i] *= f;
    ushort16* op = (t == 0 ? qb_out : (t == 1 ? k_io : v_io)) + (size_t)tok * kD + d4;
    store_b4(op, val);
    __syncthreads();
  }
}

// ---------------- V transpose with k-permutation pi(s)=(s&15)*2+(s>>4) ----------------
__global__ __launch_bounds__(256) void k_vtrans_b(const ushort16* __restrict__ v,
                                                  ushort16* __restrict__ vT) {
  __shared__ ushort16 T[64][68];
  int bh = blockIdx.y, b = bh >> 4, h = bh & 15;
  int s0 = blockIdx.x * 64;
  int tid = threadIdx.x;
#pragma unroll
  for (int p = 0; p < 4; ++p) {
    int idx = p * 1024 + tid * 4;
    int r = idx >> 6, d = idx & 63;
    *(uint2*)&T[r][d] = *(const uint2*)&v[(size_t)(b * kS + s0 + r) * kD + h * kHD + d];
  }
  __syncthreads();
#pragma unroll
  for (int p = 0; p < 16; ++p) {
    int idx = p * 256 + tid;
    int d = idx >> 6, c = idx & 63;
    int cp = (c & 32) | ((c & 15) << 1) | ((c >> 4) & 1);
    vT[((size_t)bh * kHD + d) * kS + s0 + cp] = T[c][d];
  }
}

// ---------------- MFMA flash attention, max-free; writes bf16 T IN PLACE ----------------
// QBLK=128, Ks double-buffered, Vs single, counted vmcnt pipeline (R12).
__global__ __launch_bounds__(256) void k_attn_mfma(ushort16* __restrict__ qb,
                                                   const ushort16* __restrict__ kb,
                                                   const ushort16* __restrict__ vT,
                                                   float ratio2) {
  __shared__ __align__(16) ushort16 Ks[2 * 2 * 128 * 32];  // dbuf x [dsub][key][32] swz
  __shared__ __align__(16) ushort16 Vs[4 * 64 * 32];       // [ssub][d][32] swizzled
  __shared__ __align__(16) ushort16 Ps[4 * 4 * 16 * 40];   // [wave][kk][row16][40pad]
  int bh = blockIdx.x, b = bh >> 4, h = bh & 15;
  int q0 = blockIdx.y * 128;
  int tid = threadIdx.x, lane = tid & 63, wave = tid >> 6;
  int c16 = lane & 15, quad = lane >> 4;
  int sw = (lane >> 1) & 3;
  int cbp = ((quad ^ sw) << 3);
  int wq = wave * 32;
  constexpr int NT = kS / 128;   // 8

  short8x a_q[2][2];
#pragma unroll
  for (int i = 0; i < 2; ++i)
#pragma unroll
    for (int kk = 0; kk < 2; ++kk)
      a_q[i][kk] = *(const short8x*)&qb[(size_t)(b * kS + q0 + wq + i * 16 + c16) * kD +
                                        h * kHD + kk * 32 + quad * 8];

  short8x ones;
#pragma unroll
  for (int j = 0; j < 8; ++j) ones[j] = (short)0x3F80;  // bf16 1.0

  floatx4 o[2][4], ol[2];
#pragma unroll
  for (int i = 0; i < 2; ++i) {
    ol[i] = (floatx4)0.f;
#pragma unroll
    for (int n = 0; n < 4; ++n) o[i][n] = (floatx4)0.f;
  }

  const ushort16* kbase = kb + ((size_t)b * kS) * kD + h * kHD;
  const ushort16* vbase = vT + (size_t)bh * kHD * kS;

  auto stageK = [&](int t) {
    int cbuf = t & 1;
#pragma unroll
    for (int tt = 0; tt < 2; ++tt)
#pragma unroll
      for (int cb2 = 0; cb2 < 2; ++cb2) {
        int e = cb2 * 2048 + tid * 8;
        int key = e >> 5;
        int col = ((((e >> 3) & 3) ^ ((key >> 1) & 3)) << 3);
        async16(kbase + (size_t)(t * 128 + key) * kD + tt * 32 + col,
                Ks + cbuf * 8192 + tt * 4096 + e);
      }
  };
  auto stageV = [&](int t) {
#pragma unroll
    for (int tt = 0; tt < 4; ++tt) {
      int e = tid * 8;
      int dd = e >> 5;
      int col = ((((e >> 3) & 3) ^ ((dd >> 1) & 3)) << 3);
      async16(vbase + (size_t)dd * kS + t * 128 + tt * 32 + col, Vs + tt * 2048 + e);
    }
  };

  // prologue: K(0), V(0), K(1) in flight; wait K(0) (8 newer stay in flight)
  stageK(0);
  stageV(0);
  stageK(1);
  asm volatile("s_waitcnt vmcnt(8)" ::: "memory");
  __builtin_amdgcn_s_barrier();

  for (int t = 0; t < NT; ++t) {
    const ushort16* Kc = (const ushort16*)Ks + (t & 1) * 8192;

#pragma unroll
    for (int i = 0; i < 2; ++i) {
      floatx4 s[8];
#pragma unroll
      for (int n = 0; n < 8; ++n) s[n] = (floatx4)0.f;
      __builtin_amdgcn_s_setprio(1);
#pragma unroll
      for (int kkd = 0; kkd < 2; ++kkd)
#pragma unroll
        for (int n = 0; n < 8; ++n) {
          short8x bk = *(const short8x*)&Kc[kkd * 4096 + (n * 16 + c16) * 32 + cbp];
          s[n] = __builtin_amdgcn_mfma_f32_16x16x32_bf16(a_q[i][kkd], bk, s[n], 0, 0, 0);
        }
      __builtin_amdgcn_s_setprio(0);

      // p = exp2(s); hardware packed RNE bf16 convert, permuted k
#pragma unroll
      for (int r = 0; r < 4; ++r) {
#pragma unroll
        for (int j = 0; j < 4; ++j) {
          float e0 = exp2f(s[2 * j][r]);
          float e1 = exp2f(s[2 * j + 1][r]);
          uint32 u;
          asm("v_cvt_pk_bf16_f32 %0, %1, %2" : "=v"(u) : "v"(e0), "v"(e1));
          *(uint32*)&Ps[(((wave * 4 + j) * 16) + (quad * 4 + r)) * 40 + c16 * 2] = u;
        }
      }

      if (i == 0) {
        // V(t) landed (issued one full tile ago); K(t+1)'s 4 loads stay in flight
        if (t + 1 < NT) {
          asm volatile("s_waitcnt vmcnt(4)" ::: "memory");
        } else {
          asm volatile("s_waitcnt vmcnt(0)" ::: "memory");
        }
        __builtin_amdgcn_s_barrier();
      }

      // o += P @ V ; l += P @ ones   (Ps region is per-wave: lgkm handled by compiler)
      __builtin_amdgcn_s_setprio(1);
#pragma unroll
      for (int kk = 0; kk < 4; ++kk) {
        short8x ap = *(const short8x*)&Ps[(((wave * 4 + kk) * 16) + c16) * 40 + quad * 8];
#pragma unroll
        for (int n = 0; n < 4; ++n) {
          short8x bv = *(const short8x*)&Vs[kk * 2048 + (n * 16 + c16) * 32 + cbp];
          o[i][n] = __builtin_amdgcn_mfma_f32_16x16x32_bf16(ap, bv, o[i][n], 0, 0, 0);
        }
        ol[i] = __builtin_amdgcn_mfma_f32_16x16x32_bf16(ap, ones, ol[i], 0, 0, 0);
      }
      __builtin_amdgcn_s_setprio(0);
    }

    // all waves done reading Vs & Ks[t&1]; overwrite them with next tiles
    asm volatile("s_waitcnt lgkmcnt(0)" ::: "memory");
    __builtin_amdgcn_s_barrier();
    if (t + 1 < NT) stageV(t + 1);
    if (t + 2 < NT) stageK(t + 2);
    // wait K(t+1); V(t+1)+K(t+2) (8 loads) stay in flight
    if (t + 2 < NT) {
      asm volatile("s_waitcnt vmcnt(8)" ::: "memory");
    } else if (t + 1 < NT) {
      asm volatile("s_waitcnt vmcnt(4)" ::: "memory");
    } else {
      asm volatile("s_waitcnt vmcnt(0)" ::: "memory");
    }
    __builtin_amdgcn_s_barrier();
  }

  // finalize: w = o/l, per-head rt coef; write bf16 tangent IN PLACE
#pragma unroll
  for (int i = 0; i < 2; ++i)
#pragma unroll
    for (int r = 0; r < 4; ++r) {
      float invl = 1.0f / ol[i][r];
      float w[4];
      float pssq = 0.f;
#pragma unroll
      for (int n = 0; n < 4; ++n) { w[n] = o[i][n][r] * invl; pssq += w[n] * w[n]; }
      float ssq = redSum16(pssq);
      float coef = roundtrip_scale(sqrtf(ssq)) * ratio2;
      int row = b * kS + q0 + wq + i * 16 + quad * 4 + r;
#pragma unroll
      for (int n = 0; n < 4; ++n)
        qb[(size_t)row * kD + h * kHD + n * 16 + c16] = f2b(coef * w[n]);
    }
}

// ---------------- row norm -> roundtrip scale (read-only pass) ----------------
template <int WIDTH>
__global__ __launch_bounds__(256) void k_rowscale(const ushort16* __restrict__ p,
                                                  float* __restrict__ s) {
  __shared__ float sred[4];
  constexpr int PER = WIDTH / 1024;
  size_t base = (size_t)blockIdx.x * WIDTH;
  float ss = 0.f;
#pragma unroll
  for (int i = 0; i < PER; ++i) {
    float v[4];
    load_b4(p + base + i * 1024 + threadIdx.x * 4, v);
    ss += v[0] * v[0] + v[1] * v[1] + v[2] * v[2] + v[3] * v[3];
  }
  ss = blockReduceSum256(ss, sred);
  if (threadIdx.x == 0) s[blockIdx.x] = roundtrip_scale(sqrtf(ss));
}

// ---------------- mobius epilogue core ----------------
__device__ __forceinline__ void mobius_body(float xv[4], float tv[4],
                                            const float* gp, int d4,
                                            float* sred, float outv[4]) {
  float ss = tv[0] * tv[0] + tv[1] * tv[1] + tv[2] * tv[2] + tv[3] * tv[3];
  ss = blockReduceSum256(ss, sred);
  float s5 = roundtrip_scale(sqrtf(ss));
  float gv[4];
  *(float4*)gv = *(const float4*)&gp[d4];
  float at2 = 0.f;
#pragma unroll
  for (int i = 0; i < 4; ++i) {
    float a = gv[i] * s5 * tv[i];
    tv[i] = a;
    at2 += a * a;
  }
  at2 = blockReduceSum256(at2, sred);
  float nyraw = sqrtf(at2);
  float sy = expmap0_scale(nyraw);
  float ynorm = sy * nyraw;
  float y2 = ynorm * ynorm;
  float x2p = 0.f, xyp = 0.f;
#pragma unroll
  for (int i = 0; i < 4; ++i) {
    float y = sy * tv[i];
    tv[i] = y;
    x2p += xv[i] * xv[i];
    xyp += xv[i] * y;
  }
  float x2 = blockReduceSum256(x2p, sred);
  float xy = blockReduceSum256(xyp, sred);
  float cx = 1.0f + 2.0f * xy + y2;
  float cy = 1.0f - x2;
  float den = fmaxf(1.0f + 2.0f * xy + x2 * y2, EPSF);
  float invden = 1.0f / den;
#pragma unroll
  for (int i = 0; i < 4; ++i) outv[i] = (cx * xv[i] + cy * tv[i]) * invden;
}

// final epilogue: out = mobius(xres, expmap0(g*rt(p0 + p1b)))  (p1b bf16)
__global__ __launch_bounds__(256) void k_epilogue2(const float* __restrict__ xres,
                                                   const float* __restrict__ ot0,
                                                   const ushort16* __restrict__ ot1b,
                                                   const float* __restrict__ ada,
                                                   int g_off,
                                                   float* __restrict__ out) {
  __shared__ float sred[4];
  int tok = blockIdx.x;
  int b = tok >> 10;
  size_t base = (size_t)tok * kD;
  int d4 = threadIdx.x * 4;
  float xv[4], tv[4], t1[4];
  *(float4*)tv = *(const float4*)&ot0[base + d4];
  load_b4(ot1b + base + d4, t1);
  *(float4*)xv = *(const float4*)&xres[base + d4];
#pragma unroll
  for (int i = 0; i < 4; ++i) tv[i] += t1[i];
  float outv[4];
  mobius_body(xv, tv, ada + b * 6 * kD + g_off, d4, sred, outv);
  *(float4*)&out[base + d4] = *(float4*)outv;
}

// fused: x_mid = mobius(x, msa partials) -> xmid_out (f32), then prenorm(mlp) -> bf16
__global__ __launch_bounds__(256) void k_epi_pre(const float* __restrict__ xres,
                                                 const float* __restrict__ ot0,
                                                 const ushort16* __restrict__ ot1b,
                                                 const float* __restrict__ ada,
                                                 float* __restrict__ xmid_out,
                                                 ushort16* __restrict__ lx2_out) {
  __shared__ float sred[4];
  int tok = blockIdx.x;
  int b = tok >> 10;
  size_t base = (size_t)tok * kD;
  int d4 = threadIdx.x * 4;
  float xv[4], tv[4], t1[4];
  *(float4*)tv = *(const float4*)&ot0[base + d4];
  load_b4(ot1b + base + d4, t1);
  *(float4*)xv = *(const float4*)&xres[base + d4];
#pragma unroll
  for (int i = 0; i < 4; ++i) tv[i] += t1[i];
  float xm[4];
  mobius_body(xv, tv, ada + b * 6 * kD + 2 * kD, d4, sred, xm);
  *(float4*)&xmid_out[base + d4] = *(float4*)xm;

  float ss = xm[0] * xm[0] + xm[1] * xm[1] + xm[2] * xm[2] + xm[3] * xm[3];
  ss = blockReduceSum256(ss, sred);
  float sl = logmap0_scale(sqrtf(ss));
  float sum = 0.f;
#pragma unroll
  for (int i = 0; i < 4; ++i) { xm[i] *= sl; sum += xm[i]; }
  sum = blockReduceSum256(sum, sred);
  float mean = sum * (1.0f / kD);
  float vs = 0.f;
#pragma unroll
  for (int i = 0; i < 4; ++i) { xm[i] -= mean; vs += xm[i] * xm[i]; }
  vs = blockReduceSum256(vs, sred);
  float inv = rsqrtf(vs * (1.0f / kD) + 1e-6f);
  float shv[4], scv[4];
  *(float4*)shv = *(const float4*)&ada[b * 6 * kD + 3 * kD + d4];
  *(float4*)scv = *(const float4*)&ada[b * 6 * kD + 4 * kD + d4];
  float uu = 0.f;
#pragma unroll
  for (int i = 0; i < 4; ++i) {
    float u = xm[i] * inv * (1.0f + scv[i]) + shv[i];
    xm[i] = u;
    uu += u * u;
  }
  uu = blockReduceSum256(uu, sred);
  float s = roundtrip_scale(sqrtf(uu));
#pragma unroll
  for (int i = 0; i < 4; ++i) xm[i] *= s;
  store_b4(lx2_out + base + d4, xm);
}

// ---------------------------------------------------------------------------
extern "C" void kernel_launch(void* const* d_in, const int* in_sizes, int n_in,
                              void* d_out, int out_size, void* d_ws, size_t ws_size,
                              hipStream_t stream) {
  const float* x     = (const float*)d_in[0];
  const float* t_emb = (const float*)d_in[1];
  const float* w_q = (const float*)d_in[2];  const float* b_q = (const float*)d_in[3];
  const float* w_k = (const float*)d_in[4];  const float* b_k = (const float*)d_in[5];
  const float* w_v = (const float*)d_in[6];  const float* b_v = (const float*)d_in[7];
  const float* w_o = (const float*)d_in[8];  const float* b_o = (const float*)d_in[9];
  const float* w_f1 = (const float*)d_in[10]; const float* b_f1 = (const float*)d_in[11];
  const float* w_f2 = (const float*)d_in[12]; const float* b_f2 = (const float*)d_in[13];
  const float* w_ada = (const float*)d_in[14]; const float* b_ada = (const float*)d_in[15];
  float* out = (float*)d_out;

  constexpr size_t ND = (size_t)kN * kD;    // 4 M
  constexpr size_t NF = (size_t)kN * kFF;   // 16 M
  constexpr size_t DD = (size_t)kD * kD;    // 1 M

  float* ws   = (float*)d_ws;
  float* ada  = ws;                 // 24576 f32
  float* qt   = ada + 6 * kD * kB;  // ND f32 (split-K partial 0, f32+bias)
  float* kt   = qt + ND;            // ND f32 (rowscale arrays: 4096 floats)
  float* vt   = kt + ND;            // ND f32 (x_mid)
  ushort16* qbA = (ushort16*)(vt + ND);   // ND bf16 (lx / qb / attn-T / lx2)
  ushort16* kb  = qbA + ND;               // ND bf16 (q raw -> vT -> bf16 partial1)
  ushort16* vTb = kb + ND;                // ND bf16 (k raw -> k scaled)
  ushort16* actB = vTb + ND;              // NF bf16 (v raw/scaled; h1)
  ushort16* wqT  = actB + NF;             // DD bf16 each
  ushort16* wkT  = wqT + DD;
  ushort16* wvT  = wkT + DD;
  ushort16* woT  = wvT + DD;
  ushort16* wf1T = woT + DD;              // FF*D
  ushort16* wf2T = wf1T + (size_t)kD * kFF;

  double bn = exp(lgamma(512.0) + lgamma(0.5) - lgamma(512.5));
  double bh = exp(lgamma(32.0) + lgamma(0.5) - lgamma(32.5));
  float R1 = (float)(bh / bn);
  float R2 = (float)(bn / bh);

  // 0) weight transposes + cast to bf16 [N][K]
  k_transpose4<<<dim3(16, 16, 4), 256, 0, stream>>>(w_q, w_k, w_v, w_o,
                                                    wqT, wkT, wvT, woT);
  k_transpose_bf16<<<dim3(64, 16), 256, 0, stream>>>(w_f1, wf1T, kD, kFF);
  k_transpose_bf16<<<dim3(16, 64), 256, 0, stream>>>(w_f2, wf2T, kFF, kD);
  // 1) ada
  k_ada<<<dim3(6 * kD / 64, kB), 256, 0, stream>>>(t_emb, w_ada, b_ada, ada);
  // 2) prenorm (msa): lx -> qbA (bf16)
  k_prenorm<<<kN, 256, 0, stream>>>(x, ada, 0 * kD, 1 * kD, qbA);
  // 3) q,k,v projections, bf16 out: q->kb, k->vTb, v->actB
  k_gemm_bf16<1, 1><<<dim3(kN / 128, kD / 128, 3), 256, 0, stream>>>(
      qbA, wqT, wkT, wvT, b_q, b_k, b_v, nullptr, kb, vTb, actB, kN, kD, kD);
  // 4) head split: qb->qbA (pre-scaled 0.125*log2e), k in vTb, v in actB
  k_headsplit_b<<<kN, 256, 0, stream>>>(kb, vTb, actB, qbA, R1);
  // 5) V transpose (k-permuted): actB -> kb
  k_vtrans_b<<<dim3(kS / 64, kB * kH), 256, 0, stream>>>(actB, kb);
  // 6) attention (max-free): reads qbA, writes bf16 tangent T in place
  k_attn_mfma<<<dim3(kB * kH, kS / 128), 256, 0, stream>>>(qbA, vTb, kb, R2);
  // 7) row scales for the concat-roundtrip: s[tok] from |T| -> kt
  k_rowscale<kD><<<kN, 256, 0, stream>>>(qbA, kt);
  // 8) o projection, split-K=2, row-scaled: partials qt (f32,+bias), kb (bf16)
  k_gemm_bf16<0, 2><<<dim3(kN / 128, kD / 128, 2), 256, 0, stream>>>(
      qbA, woT, woT, woT, b_o, b_o, b_o, kt, qt, kb, nullptr, kN, kD, kD);
  // 9+10) fused mobius epilogue (msa) + prenorm (mlp): vt <- x_mid, qbA <- lx2
  k_epi_pre<<<kN, 256, 0, stream>>>(x, qt, kb, ada, vt, qbA);
  // 11) f1 -> actB (raw h1, bf16)
  k_gemm_bf16<1, 1><<<dim3(kN / 128, kFF / 128, 1), 256, 0, stream>>>(
      qbA, wf1T, wf1T, wf1T, b_f1, b_f1, b_f1, nullptr, actB, actB, actB, kN, kFF, kD);
  // 12) row scales for rt(h1) -> kt
  k_rowscale<kFF><<<kN, 256, 0, stream>>>(actB, kt);
  // 13) f2, split-K=2, row-scaled: partials qt (f32,+bias), kb (bf16)
  k_gemm_bf16<0, 2><<<dim3(kN / 128, kD / 128, 2), 256, 0, stream>>>(
      actB, wf2T, wf2T, wf2T, b_f2, b_f2, b_f2, kt, qt, kb, nullptr, kN, kD, kFF);
  // 14) mobius epilogue (mlp): out = mobius(vt, qt + kb)
  k_epilogue2<<<kN, 256, 0, stream>>>(vt, qt, kb, ada, 5 * kD, out);

  (void)in_sizes; (void)n_in; (void)out_size; (void)ws_size;
}